// Round 11
// baseline (195.937 us; speedup 1.0000x reference)
//
#include <hip/hip_runtime.h>
#include <stdint.h>

#define NB    1024   // batch
#define NUM   512    // nodes
#define HD    64     // hidden dim
#define NE    4096   // edges
#define NEP   4608   // padded edge capacity
#define MAIN  10     // softmax segment

typedef _Float16 hlf;
typedef __attribute__((ext_vector_type(2))) _Float16 hlf2;
typedef __attribute__((ext_vector_type(8))) _Float16 hlf8;
typedef __attribute__((ext_vector_type(4))) float f32x4;

__device__ __forceinline__ unsigned short f2h(float f) {
    hlf v = (hlf)f;
    return __builtin_bit_cast(unsigned short, v);
}

// ---------------------------------------------------------------------------
// Prep: block 0 builds degree-sorted CSR (for SpMM3) + scatters dense S32;
// blocks 1..72 build E1T = (emb@W1)^T and W2T = W2^T in f16.
// ---------------------------------------------------------------------------
__global__ __launch_bounds__(512) void prep_all(
    const int* __restrict__ erow, const int* __restrict__ ecol,
    const float* __restrict__ emb, const float* __restrict__ W1,
    const float* __restrict__ W2,
    int* __restrict__ rsptr, int* __restrict__ colmap, int* __restrict__ epk,
    short* __restrict__ E1T, short* __restrict__ W2T,
    float* __restrict__ S32)
{
    const int t = threadIdx.x;
    if (blockIdx.x != 0) {
        int g = (blockIdx.x - 1) * 512 + t;     // 72 x 512 = 36864
        if (g < NUM * HD) {
            int dim = g >> 9, node = g & 511;   // E1T layout [dim][node]
            float acc = 0.0f;
            #pragma unroll
            for (int k = 0; k < HD; ++k) acc += emb[node * HD + k] * W1[k * HD + dim];
            E1T[g] = (short)f2h(acc);
        } else if (g < NUM * HD + HD * HD) {
            int j = g - NUM * HD;
            int dout = j >> 6, din = j & 63;
            W2T[j] = (short)f2h(W2[din * HD + dout]);
        }
        return;
    }

    __shared__ int   sdeg[NUM];
    __shared__ int   aux[NUM];
    __shared__ float sdv[NUM];
    __shared__ int   rnk[NUM];
    __shared__ int   rdg[NUM];
    __shared__ int   wsum[8];

    const int lane = t & 63, wv = t >> 6;

    sdeg[t] = 0; aux[t] = 0;
    __syncthreads();
    for (int e = t; e < NE; e += 512) atomicAdd(&sdeg[ecol[e]], 1);
    __syncthreads();
    const int deg  = sdeg[t];
    const int pdeg = (deg + 1) & ~1;
    const int dbin = deg < NUM ? deg : NUM - 1;
    sdv[t] = deg > 0 ? rsqrtf((float)deg) : 0.0f;
    atomicAdd(&aux[dbin], 1);
    __syncthreads();
    {
        int v = aux[t];
        #pragma unroll
        for (int ofs = 1; ofs < 64; ofs <<= 1) {
            int sh = __shfl_up(v, ofs, 64);
            if (lane >= ofs) v += sh;
        }
        if (lane == 63) wsum[wv] = v;
        __syncthreads();
        if (t == 0) {
            int s = 0;
            #pragma unroll
            for (int w = 0; w < 8; ++w) { int tmp = wsum[w]; wsum[w] = s; s += tmp; }
        }
        __syncthreads();
        int inc = v + wsum[wv];
        aux[t]  = inc;
        __syncthreads();
        sdeg[t] = (t == 0) ? 0 : aux[t - 1];
        __syncthreads();
    }
    {
        int r = atomicAdd(&sdeg[dbin], 1);
        rnk[t] = r;
        rdg[r] = pdeg;
        colmap[r] = t;
    }
    __syncthreads();
    {
        int dv = rdg[t], v = dv;
        #pragma unroll
        for (int ofs = 1; ofs < 64; ofs <<= 1) {
            int sh = __shfl_up(v, ofs, 64);
            if (lane >= ofs) v += sh;
        }
        if (lane == 63) wsum[wv] = v;
        __syncthreads();
        if (t == 0) {
            int s = 0;
            #pragma unroll
            for (int w = 0; w < 8; ++w) { int tmp = wsum[w]; wsum[w] = s; s += tmp; }
        }
        __syncthreads();
        int inc  = v + wsum[wv];
        int excl = inc - dv;
        rsptr[t] = excl;
        if (t == NUM - 1) rsptr[NUM] = inc;
        aux[t] = excl;
        __syncthreads();
    }
    sdeg[t] = aux[rnk[t]];
    __syncthreads();
    for (int i = t; i < NEP; i += 512) epk[i] = 0;
    __syncthreads();
    for (int e = t; e < NE; e += 512) {
        int c = ecol[e], rr = erow[e];
        int p = atomicAdd(&sdeg[c], 1);
        float nf = sdv[rr] * sdv[c];
        unsigned ns = (unsigned)f2h(nf);
        epk[p] = (rr << 16) | (int)ns;          // hi16 = row index
        atomicAdd(&S32[c * NUM + rr], nf);      // dense S (dup edges accumulate)
    }
}

// ---------------------------------------------------------------------------
// Cast S32 -> Sfr: f16 in MFMA A-fragment order. Fragment f = mt*16+kt holds
// the 16x32 tile A[mt*16 .. +16][kt*32 .. +32]; lane l owns row (l&15),
// k-chunk (l>>4)*8 — stored at Sfr + f*1024B + l*16B (wave load = 1KB coalesced)
// ---------------------------------------------------------------------------
__global__ __launch_bounds__(1024) void cast_S(
    const float* __restrict__ S32, hlf* __restrict__ Sfr)
{
    int idx = blockIdx.x * 1024 + threadIdx.x;  // 0..32767 = 512 frags x 64 lanes
    int f = idx >> 6, l = idx & 63;
    int mt = f >> 4, kt = f & 15;
    int c  = mt * 16 + (l & 15);
    int r0 = kt * 32 + (l >> 4) * 8;
    const float* src = S32 + c * NUM + r0;
    hlf8 o;
    #pragma unroll
    for (int j = 0; j < 8; ++j) o[j] = (hlf)src[j];
    *(hlf8*)(Sfr + idx * 8) = o;
}

// ---------------------------------------------------------------------------
// Body: one block (1024 thr, 16 waves) per batch element; 2 blocks/CU forced
// via launch_bounds(1024,8). Peak TOTAL regs (arch+acc) kept <= 64 by
// processing the two mt-tiles sequentially (acc = 16 regs at a time; finished
// tile packed to f16 in 8 regs before the next starts).
// 71.5 KB LDS: single HT buffer time-shared across phases via barriers.
// ---------------------------------------------------------------------------
__global__ __launch_bounds__(1024, 8) void gcn_body(
    const float* __restrict__ x, const hlf* __restrict__ E1T,
    const hlf* __restrict__ W2T, const hlf* __restrict__ Sfr,
    const float* __restrict__ b1, const float* __restrict__ b2,
    const float* __restrict__ W3, const float* __restrict__ b3,
    const int* __restrict__ rsptrg, const int* __restrict__ cmapg,
    const int* __restrict__ epkg,
    float* __restrict__ out)
{
    __shared__ hlf   HT[HD * NUM];   // 64KB, time-shared: H0^T / h1^T / agg2
    __shared__ float xs[NUM];
    __shared__ float tv[NUM];
    __shared__ float slog[NUM];
    __shared__ float sred[2];

    const int t    = threadIdx.x;
    const int b    = blockIdx.x;
    const int lane = t & 63;
    const int wave = t >> 6;           // 0..15
    const int q    = lane >> 4;        // 0..3
    const int l15  = lane & 15;

    if (t < NUM) xs[t] = x[b * NUM + t];
    __syncthreads();

    // ---- build H0^T[d][r] = x[r]*E1[r][d], swizzled
    #pragma unroll
    for (int p = 0; p < 4; ++p) {
        int i = t + p * 1024;          // 4096 chunks of 8
        int d = i >> 6, r0 = (i & 63) * 8;
        hlf8 ev = *(const hlf8*)&E1T[d * NUM + r0];
        hlf8 o;
        #pragma unroll
        for (int j = 0; j < 8; ++j) o[j] = ev[j] * (hlf)xs[r0 + j];
        *(hlf8*)((char*)HT + d * 1024 + ((r0 * 2) ^ ((d & 7) << 4))) = o;
    }
    __syncthreads();

// one mt-tile of S @ HT: acc[4] (16 regs), af streamed from L2, bf from LDS
#define SMM_TILE(MT, ACC)                                                     \
    {                                                                         \
        _Pragma("unroll")                                                     \
        for (int nt = 0; nt < 4; ++nt) ACC[nt] = (f32x4){0.f, 0.f, 0.f, 0.f}; \
        _Pragma("unroll 1")                                                   \
        for (int kt = 0; kt < 16; ++kt) {                                     \
            hlf8 af = *(const hlf8*)((const char*)Sfr +                       \
                          (((MT) * 16 + kt) << 10) + lane * 16);              \
            _Pragma("unroll")                                                 \
            for (int nt = 0; nt < 4; ++nt) {                                  \
                int row = nt * 16 + l15;                                      \
                hlf8 bf = *(const hlf8*)((const char*)HT + row * 1024 +       \
                              ((kt * 64 + q * 16) ^ ((row & 7) << 4)));       \
                ACC[nt] = __builtin_amdgcn_mfma_f32_16x16x32_f16(             \
                    af, bf, ACC[nt], 0, 0, 0);                                \
            }                                                                 \
        }                                                                     \
    }

    // ---- layer1: agg1 = S@H0; h1 = relu(agg1 + b1) packed pre-barrier
    {
        uint2 pkA[4], pkB[4];
        {
            f32x4 acc[4];
            SMM_TILE(wave * 2 + 0, acc)
            #pragma unroll
            for (int nt = 0; nt < 4; ++nt) {
                float bb = b1[nt * 16 + l15];
                pkA[nt].x = __builtin_bit_cast(unsigned, __builtin_amdgcn_cvt_pkrtz(
                                fmaxf(acc[nt][0] + bb, 0.0f),
                                fmaxf(acc[nt][1] + bb, 0.0f)));
                pkA[nt].y = __builtin_bit_cast(unsigned, __builtin_amdgcn_cvt_pkrtz(
                                fmaxf(acc[nt][2] + bb, 0.0f),
                                fmaxf(acc[nt][3] + bb, 0.0f)));
            }
        }
        {
            f32x4 acc[4];
            SMM_TILE(wave * 2 + 1, acc)
            #pragma unroll
            for (int nt = 0; nt < 4; ++nt) {
                float bb = b1[nt * 16 + l15];
                pkB[nt].x = __builtin_bit_cast(unsigned, __builtin_amdgcn_cvt_pkrtz(
                                fmaxf(acc[nt][0] + bb, 0.0f),
                                fmaxf(acc[nt][1] + bb, 0.0f)));
                pkB[nt].y = __builtin_bit_cast(unsigned, __builtin_amdgcn_cvt_pkrtz(
                                fmaxf(acc[nt][2] + bb, 0.0f),
                                fmaxf(acc[nt][3] + bb, 0.0f)));
            }
        }
        __syncthreads();   // all H0 reads done; HT reusable as h1^T
        #pragma unroll
        for (int nt = 0; nt < 4; ++nt) {
            int n = nt * 16 + l15;
            *(uint2*)((char*)HT + n * 1024 +
                      (((wave * 2 + 0) * 32 + q * 8) ^ ((n & 7) << 4))) = pkA[nt];
            *(uint2*)((char*)HT + n * 1024 +
                      (((wave * 2 + 1) * 32 + q * 8) ^ ((n & 7) << 4))) = pkB[nt];
        }
    }
    __syncthreads();

    // ---- layer2: agg2 = S@h1, packed raw f16 pre-barrier -> HT row-major swz
    {
        uint2 qkA[4], qkB[4];
        {
            f32x4 acc[4];
            SMM_TILE(wave * 2 + 0, acc)
            #pragma unroll
            for (int nt = 0; nt < 4; ++nt) {
                qkA[nt].x = __builtin_bit_cast(unsigned,
                                __builtin_amdgcn_cvt_pkrtz(acc[nt][0], acc[nt][1]));
                qkA[nt].y = __builtin_bit_cast(unsigned,
                                __builtin_amdgcn_cvt_pkrtz(acc[nt][2], acc[nt][3]));
            }
        }
        {
            f32x4 acc[4];
            SMM_TILE(wave * 2 + 1, acc)
            #pragma unroll
            for (int nt = 0; nt < 4; ++nt) {
                qkB[nt].x = __builtin_bit_cast(unsigned,
                                __builtin_amdgcn_cvt_pkrtz(acc[nt][0], acc[nt][1]));
                qkB[nt].y = __builtin_bit_cast(unsigned,
                                __builtin_amdgcn_cvt_pkrtz(acc[nt][2], acc[nt][3]));
            }
        }
        __syncthreads();   // all h1 reads done; HT reusable as agg2
        #pragma unroll
        for (int nt = 0; nt < 4; ++nt) {
            int n = nt * 16 + l15;
            #pragma unroll
            for (int i = 0; i < 4; ++i) {
                hlf2 hA = __builtin_bit_cast(hlf2, (i < 2) ? qkA[nt].x : qkA[nt].y);
                hlf2 hB = __builtin_bit_cast(hlf2, (i < 2) ? qkB[nt].x : qkB[nt].y);
                int mA = (wave * 2 + 0) * 16 + q * 4 + i;
                int mB = (wave * 2 + 1) * 16 + q * 4 + i;
                *(hlf*)((char*)HT + mA * 128 + ((n * 2) ^ ((mA & 7) << 4))) = hA[i & 1];
                *(hlf*)((char*)HT + mB * 128 + ((n * 2) ^ ((mB & 7) << 4))) = hB[i & 1];
            }
        }
    }
    __syncthreads();

    // ---- z2 = agg2@W2 + b2; tv[node] = sum_n relu(z2).W3
    {
        #pragma unroll 1
        for (int mm = 0; mm < 2; ++mm) {
            int mt = wave * 2 + mm;
            f32x4 z[4];
            #pragma unroll
            for (int nt = 0; nt < 4; ++nt) z[nt] = (f32x4){0.f, 0.f, 0.f, 0.f};
            #pragma unroll
            for (int kt = 0; kt < 2; ++kt) {
                int m = mt * 16 + l15;
                hlf8 af = *(const hlf8*)((const char*)HT + m * 128 +
                              ((kt * 64 + q * 16) ^ ((m & 7) << 4)));
                #pragma unroll
                for (int nt = 0; nt < 4; ++nt) {
                    hlf8 wb = *(const hlf8*)&W2T[(nt * 16 + l15) * HD +
                                                 kt * 32 + q * 8];
                    z[nt] = __builtin_amdgcn_mfma_f32_16x16x32_f16(
                        af, wb, z[nt], 0, 0, 0);
                }
            }
            float vs[4] = {0.f, 0.f, 0.f, 0.f};
            #pragma unroll
            for (int nt = 0; nt < 4; ++nt) {
                int n = nt * 16 + l15;
                float bb = b2[n], ww = W3[n];
                #pragma unroll
                for (int i = 0; i < 4; ++i)
                    vs[i] += fmaxf(z[nt][i] + bb, 0.0f) * ww;
            }
            #pragma unroll
            for (int i = 0; i < 4; ++i) {
                float v = vs[i];
                v += __shfl_xor(v, 1, 64);
                v += __shfl_xor(v, 2, 64);
                v += __shfl_xor(v, 4, 64);
                v += __shfl_xor(v, 8, 64);
                if (l15 == 0) tv[mt * 16 + q * 4 + i] = v;
            }
        }
    }
    __syncthreads();

    // ---- SpMM3: slog[col] = (S @ tv)[col] + b3   (2 threads per rank)
    {
        int rk = t >> 1, hh = t & 1;
        int e0 = rsptrg[rk], e1 = rsptrg[rk + 1];
        int mid = (e0 + e1) >> 1;
        int ea = hh ? mid : e0;
        int eb = hh ? e1 : mid;
        float acc = 0.0f;
        for (int e = ea; e < eb; ++e) {
            unsigned pe = (unsigned)epkg[e];
            float nf = (float)__builtin_bit_cast(hlf2, pe)[0];
            acc = fmaf(nf, tv[pe >> 16], acc);
        }
        acc += __shfl_xor(acc, 1, 64);
        if (!hh) slog[cmapg[rk]] = acc + b3[0];
    }
    __syncthreads();

    // ---- softmax stats over [0, MAIN)
    if (t < 64) {
        float v = (t < MAIN) ? slog[t] : -1e30f;
        float m = v;
        m = fmaxf(m, __shfl_xor(m, 1, 64));
        m = fmaxf(m, __shfl_xor(m, 2, 64));
        m = fmaxf(m, __shfl_xor(m, 4, 64));
        m = fmaxf(m, __shfl_xor(m, 8, 64));
        float ev = (t < MAIN) ? __expf(v - m) : 0.0f;
        ev += __shfl_xor(ev, 1, 64);
        ev += __shfl_xor(ev, 2, 64);
        ev += __shfl_xor(ev, 4, 64);
        ev += __shfl_xor(ev, 8, 64);
        if (t == 0) { sred[0] = m; sred[1] = ev; }
    }
    __syncthreads();

    if (t < NUM) {
        float l = slog[t];
        float o = (t < MAIN) ? __expf(l - sred[0]) / sred[1]
                             : 1.0f / (1.0f + __expf(-l));
        out[b * NUM + t] = o;
    }
#undef SMM_TILE
}

// ---------------------------------------------------------------------------
extern "C" void kernel_launch(void* const* d_in, const int* in_sizes, int n_in,
                              void* d_out, int out_size, void* d_ws, size_t ws_size,
                              hipStream_t stream) {
    const float* x    = (const float*)d_in[0];
    const float* emb  = (const float*)d_in[1];
    const float* W1   = (const float*)d_in[2];
    const float* b1   = (const float*)d_in[3];
    const float* W2   = (const float*)d_in[4];
    const float* b2   = (const float*)d_in[5];
    const float* W3   = (const float*)d_in[6];
    const float* b3   = (const float*)d_in[7];
    const int*   erow = (const int*)d_in[8];
    const int*   ecol = (const int*)d_in[9];

    char* ws = (char*)d_ws;
    float* S32   = (float*)ws;               // 1 MB   [0, 1048576)
    short* Sfr   = (short*)(ws + 1048576);   // 512 KB [1048576, 1572864)
    short* E1T   = (short*)(ws + 1572864);   // 64 KB  [1572864, 1638400)
    short* W2T   = (short*)(ws + 1638400);   // 8 KB   [1638400, 1646592)
    int*   epk   = (int*)(ws + 1646592);     // 18 KB  [1646592, 1665024)
    int*   rsptr = (int*)(ws + 1665024);     // 2052 B
    int*   colmap= (int*)(ws + 1667200);     // 2048 B

    hipMemsetAsync(S32, 0, NUM * NUM * sizeof(float), stream);
    prep_all<<<73, 512, 0, stream>>>(erow, ecol, emb, W1, W2,
                                     rsptr, colmap, epk, E1T, W2T, S32);
    cast_S<<<32, 1024, 0, stream>>>(S32, (hlf*)Sfr);
    gcn_body<<<NB, 1024, 0, stream>>>(x, (const hlf*)E1T, (const hlf*)W2T,
                                      (const hlf*)Sfr, b1, b2, W3, b3,
                                      rsptr, colmap, epk, (float*)d_out);
}

// Round 12
// 182.582 us; speedup vs baseline: 1.0731x; 1.0731x over previous
//
#include <hip/hip_runtime.h>
#include <stdint.h>

#define NB    1024   // batch
#define NUM   512    // nodes
#define HD    64     // hidden dim
#define NE    4096   // edges
#define NEP   4608   // padded edge capacity (each column padded to even count)
#define MAIN  10     // softmax segment

typedef _Float16 hlf;
typedef __attribute__((ext_vector_type(2))) _Float16 hlf2;
typedef __attribute__((ext_vector_type(8))) _Float16 hlf8;
typedef __attribute__((ext_vector_type(4))) float f32x4;

__device__ __forceinline__ unsigned short f2h(float f) {
    hlf v = (hlf)f;
    return __builtin_bit_cast(unsigned short, v);
}

// ---------------------------------------------------------------------------
// Prep (identical to the 154.7us R6 kernel): block 0 builds degree-sorted,
// even-padded CSR via wave-shfl scans; blocks 1..72 cast E1 = emb@W1 and
// W2T = W2^T to f16. Edge pack: epk = (row << 23) | f16(norm) -> hi16 is a
// 128B-row byte offset.
// ---------------------------------------------------------------------------
__global__ __launch_bounds__(512) void prep_all(
    const int* __restrict__ erow, const int* __restrict__ ecol,
    const float* __restrict__ emb, const float* __restrict__ W1,
    const float* __restrict__ W2,
    int* __restrict__ rsptr, int* __restrict__ colmap, int* __restrict__ epk,
    short* __restrict__ E1, short* __restrict__ W2T)
{
    const int t = threadIdx.x;
    if (blockIdx.x != 0) {
        int g = (blockIdx.x - 1) * 512 + t;     // 72 x 512 = 36864
        if (g < NUM * HD) {
            int node = g >> 6, dim = g & 63;
            float acc = 0.0f;
            #pragma unroll
            for (int k = 0; k < HD; ++k) acc += emb[node * HD + k] * W1[k * HD + dim];
            E1[g] = (short)f2h(acc);
        } else if (g < NUM * HD + HD * HD) {
            int j = g - NUM * HD;
            int dout = j >> 6, din = j & 63;
            W2T[j] = (short)f2h(W2[din * HD + dout]);
        }
        return;
    }

    __shared__ int   sdeg[NUM];
    __shared__ int   aux[NUM];
    __shared__ float sdv[NUM];
    __shared__ int   rnk[NUM];
    __shared__ int   rdg[NUM];
    __shared__ int   wsum[8];

    const int lane = t & 63, wv = t >> 6;

    sdeg[t] = 0; aux[t] = 0;
    __syncthreads();
    for (int e = t; e < NE; e += 512) atomicAdd(&sdeg[ecol[e]], 1);
    __syncthreads();
    const int deg  = sdeg[t];
    const int pdeg = (deg + 1) & ~1;            // pad to even
    const int dbin = deg < NUM ? deg : NUM - 1;
    sdv[t] = deg > 0 ? rsqrtf((float)deg) : 0.0f;
    atomicAdd(&aux[dbin], 1);
    __syncthreads();
    {
        int v = aux[t];
        #pragma unroll
        for (int ofs = 1; ofs < 64; ofs <<= 1) {
            int sh = __shfl_up(v, ofs, 64);
            if (lane >= ofs) v += sh;
        }
        if (lane == 63) wsum[wv] = v;
        __syncthreads();
        if (t == 0) {
            int s = 0;
            #pragma unroll
            for (int w = 0; w < 8; ++w) { int tmp = wsum[w]; wsum[w] = s; s += tmp; }
        }
        __syncthreads();
        int inc = v + wsum[wv];
        aux[t]  = inc;
        __syncthreads();
        sdeg[t] = (t == 0) ? 0 : aux[t - 1];
        __syncthreads();
    }
    {
        int r = atomicAdd(&sdeg[dbin], 1);      // degree-sorted rank
        rnk[t] = r;
        rdg[r] = pdeg;
        colmap[r] = t;
    }
    __syncthreads();
    {
        int dv = rdg[t], v = dv;
        #pragma unroll
        for (int ofs = 1; ofs < 64; ofs <<= 1) {
            int sh = __shfl_up(v, ofs, 64);
            if (lane >= ofs) v += sh;
        }
        if (lane == 63) wsum[wv] = v;
        __syncthreads();
        if (t == 0) {
            int s = 0;
            #pragma unroll
            for (int w = 0; w < 8; ++w) { int tmp = wsum[w]; wsum[w] = s; s += tmp; }
        }
        __syncthreads();
        int inc  = v + wsum[wv];
        int excl = inc - dv;
        rsptr[t] = excl;
        if (t == NUM - 1) rsptr[NUM] = inc;
        aux[t] = excl;
        __syncthreads();
    }
    sdeg[t] = aux[rnk[t]];
    __syncthreads();
    for (int i = t; i < NEP; i += 512) epk[i] = 0;
    __syncthreads();
    for (int e = t; e < NE; e += 512) {
        int c = ecol[e], rr = erow[e];
        int p = atomicAdd(&sdeg[c], 1);
        unsigned ns = (unsigned)f2h(sdv[rr] * sdv[c]);
        epk[p] = (rr << 23) | (int)ns;          // hi16 = row*128 (byte offset)
    }
}

// ---------------------------------------------------------------------------
// Body: one block (1024 thr, 16 waves) per batch element; 2 blocks/CU
// (73.7 KB LDS). Single 64 KB H buffer, in-place: B1 -> h1 -> g, with
// outputs held packed in registers across the read/write barrier.
// Edges read from GLOBAL epkg (18 KB, L1-resident, shared by both blocks).
//   SpMM1: h1 = relu(S@B1 + b1)      gathers H(B1); holds h1 packed (16 regs)
//   MFMA : g = h1@W2                 reads H(h1); holds g packed (16 regs)
//   SpMM2: tv[c] = sum relu((S@g)+b2).W3   gathers H(g), writes tv (LDS)
//   SpMM3: logits = S@tv + b3; softmax/sigmoid
// ---------------------------------------------------------------------------
__global__ __launch_bounds__(1024, 8) void gcn_body(
    const float* __restrict__ x, const hlf* __restrict__ E1,
    const hlf* __restrict__ W2T,
    const float* __restrict__ b1, const float* __restrict__ b2,
    const float* __restrict__ W3, const float* __restrict__ b3,
    const int* __restrict__ rsptrg, const int* __restrict__ colmapg,
    const int* __restrict__ epkg,
    float* __restrict__ out)
{
    __shared__ hlf   H[NUM * HD];      // 65536 B, time-shared: B1 / h1 / g
    __shared__ int   sptr[513];
    __shared__ int   cmap[NUM];
    __shared__ float tv[NUM];
    __shared__ float slog[NUM];
    __shared__ float sred[2];

    const int t     = threadIdx.x;
    const int b     = blockIdx.x;
    const int lane  = t & 63;
    const int wave  = t >> 6;          // 0..15
    const int q     = lane >> 4;
    const int l15   = lane & 15;
    const int grp   = lane >> 3;       // column slot within wave
    const int dbase = (lane & 7) * 8;  // this lane's 8-dim strip

    if (t < 513) sptr[t] = rsptrg[t];
    if (t < NUM) cmap[t] = colmapg[t];

    // ---- build H = B1: B1[r][d] = x[b,r] * E1[r][d]   (f16 storage)
    #pragma unroll
    for (int p = 0; p < 4; ++p) {
        int i = t + p * 1024;
        int r = i >> 3, d8 = (i & 7) * 8;
        float xr = x[b * NUM + r];
        hlf  xh = (hlf)xr;
        hlf8 e  = *(const hlf8*)&E1[r * HD + d8];
        hlf8 o;
        #pragma unroll
        for (int j = 0; j < 8; ++j) o[j] = e[j] * xh;
        *(hlf8*)&H[r * HD + d8] = o;
    }
    const char* Hb = (const char*)H + dbase * 2;   // per-lane gather base
    __syncthreads();

// 8 f16->f32 mixed FMAs into acc; norm is the low f16 half of pe
#define MACROW(acc, hv, pe) {                                                 \
        const hlf nh = __builtin_bit_cast(hlf2, (unsigned)(pe))[0];           \
        const hlf2 p0 = __builtin_bit_cast(hlf2, (hv).x);                     \
        const hlf2 p1 = __builtin_bit_cast(hlf2, (hv).y);                     \
        const hlf2 p2 = __builtin_bit_cast(hlf2, (hv).z);                     \
        const hlf2 p3 = __builtin_bit_cast(hlf2, (hv).w);                     \
        acc[0] = fmaf((float)p0[0], (float)nh, acc[0]);                       \
        acc[1] = fmaf((float)p0[1], (float)nh, acc[1]);                       \
        acc[2] = fmaf((float)p1[0], (float)nh, acc[2]);                       \
        acc[3] = fmaf((float)p1[1], (float)nh, acc[3]);                       \
        acc[4] = fmaf((float)p2[0], (float)nh, acc[4]);                       \
        acc[5] = fmaf((float)p2[1], (float)nh, acc[5]);                       \
        acc[6] = fmaf((float)p3[0], (float)nh, acc[6]);                       \
        acc[7] = fmaf((float)p3[1], (float)nh, acc[7]); }

    // ---- SpMM1: h1 = relu(S@B1 + b1); hold packed per set, write after barrier
    {
        uint4 hv[4];
        #pragma unroll 1
        for (int set = 0; set < 4; ++set) {
            int r  = set * 128 + wave * 8 + grp;
            int e0 = sptr[r], e1 = sptr[r + 1];
            float a[8];
            #pragma unroll
            for (int j = 0; j < 8; ++j) a[j] = 0.0f;
            for (int e = e0; e < e1; e += 2) {     // even-padded: exact
                int2 qa = *(const int2*)&epkg[e];
                uint4 c0 = *(const uint4*)(Hb + ((unsigned)qa.x >> 16));
                uint4 c1 = *(const uint4*)(Hb + ((unsigned)qa.y >> 16));
                MACROW(a, c0, qa.x) MACROW(a, c1, qa.y)
            }
            f32x4 u0 = *(const f32x4*)&b1[dbase];
            f32x4 u1 = *(const f32x4*)&b1[dbase + 4];
            hv[set].x = __builtin_bit_cast(unsigned, __builtin_amdgcn_cvt_pkrtz(
                            fmaxf(a[0] + u0[0], 0.0f), fmaxf(a[1] + u0[1], 0.0f)));
            hv[set].y = __builtin_bit_cast(unsigned, __builtin_amdgcn_cvt_pkrtz(
                            fmaxf(a[2] + u0[2], 0.0f), fmaxf(a[3] + u0[3], 0.0f)));
            hv[set].z = __builtin_bit_cast(unsigned, __builtin_amdgcn_cvt_pkrtz(
                            fmaxf(a[4] + u1[0], 0.0f), fmaxf(a[5] + u1[1], 0.0f)));
            hv[set].w = __builtin_bit_cast(unsigned, __builtin_amdgcn_cvt_pkrtz(
                            fmaxf(a[6] + u1[2], 0.0f), fmaxf(a[7] + u1[3], 0.0f)));
        }
        __syncthreads();   // all B1 gathers complete
        #pragma unroll
        for (int set = 0; set < 4; ++set) {
            int r = set * 128 + wave * 8 + grp;
            *(uint4*)&H[cmap[r] * HD + dbase] = hv[set];
        }
    }
    __syncthreads();

    // ---- MFMA: g = h1 @ W2 (raw, bias applied post-aggregation);
    //      acc one nt at a time (4 regs), hold g packed (16 regs)
    {
        uint2 gk[2][4];
        #pragma unroll 1
        for (int mm = 0; mm < 2; ++mm) {
            int m = wave * 32 + mm * 16 + l15;
            hlf8 a0 = *(const hlf8*)&H[m * HD + q * 8];
            hlf8 a1 = *(const hlf8*)&H[m * HD + 32 + q * 8];
            #pragma unroll
            for (int nt = 0; nt < 4; ++nt) {
                hlf8 w0 = *(const hlf8*)&W2T[(nt * 16 + l15) * HD + q * 8];
                hlf8 w1 = *(const hlf8*)&W2T[(nt * 16 + l15) * HD + 32 + q * 8];
                f32x4 acc = (f32x4){0.f, 0.f, 0.f, 0.f};
                acc = __builtin_amdgcn_mfma_f32_16x16x32_f16(a0, w0, acc, 0, 0, 0);
                acc = __builtin_amdgcn_mfma_f32_16x16x32_f16(a1, w1, acc, 0, 0, 0);
                gk[mm][nt].x = __builtin_bit_cast(unsigned,
                                   __builtin_amdgcn_cvt_pkrtz(acc[0], acc[1]));
                gk[mm][nt].y = __builtin_bit_cast(unsigned,
                                   __builtin_amdgcn_cvt_pkrtz(acc[2], acc[3]));
            }
        }
        __syncthreads();   // all h1 reads complete
        #pragma unroll
        for (int mm = 0; mm < 2; ++mm)
            #pragma unroll
            for (int nt = 0; nt < 4; ++nt) {
                int mrow = wave * 32 + mm * 16 + q * 4;
                hlf2 lo = __builtin_bit_cast(hlf2, gk[mm][nt].x);
                hlf2 hi = __builtin_bit_cast(hlf2, gk[mm][nt].y);
                H[(mrow + 0) * HD + nt * 16 + l15] = lo[0];
                H[(mrow + 1) * HD + nt * 16 + l15] = lo[1];
                H[(mrow + 2) * HD + nt * 16 + l15] = hi[0];
                H[(mrow + 3) * HD + nt * 16 + l15] = hi[1];
            }
    }
    __syncthreads();

    // ---- SpMM2 + fused epilogue: tv[c] = sum_d relu((S@g)[c,d] + b2[d]) * W3[d]
    #pragma unroll 1
    for (int set = 0; set < 4; ++set) {
        int r  = set * 128 + wave * 8 + grp;
        int e0 = sptr[r], e1 = sptr[r + 1];
        int c  = cmap[r];
        float a[8];
        #pragma unroll
        for (int j = 0; j < 8; ++j) a[j] = 0.0f;
        int e = e0;
        for (; e + 4 <= e1; e += 4) {
            int2 qa = *(const int2*)&epkg[e];
            int2 qb = *(const int2*)&epkg[e + 2];
            uint4 c0 = *(const uint4*)(Hb + ((unsigned)qa.x >> 16));
            uint4 c1 = *(const uint4*)(Hb + ((unsigned)qa.y >> 16));
            uint4 c2 = *(const uint4*)(Hb + ((unsigned)qb.x >> 16));
            uint4 c3 = *(const uint4*)(Hb + ((unsigned)qb.y >> 16));
            MACROW(a, c0, qa.x) MACROW(a, c1, qa.y)
            MACROW(a, c2, qb.x) MACROW(a, c3, qb.y)
        }
        if (e < e1) {
            int2 qa = *(const int2*)&epkg[e];
            uint4 c0 = *(const uint4*)(Hb + ((unsigned)qa.x >> 16));
            uint4 c1 = *(const uint4*)(Hb + ((unsigned)qa.y >> 16));
            MACROW(a, c0, qa.x) MACROW(a, c1, qa.y)
        }
        f32x4 v0 = *(const f32x4*)&b2[dbase], v1 = *(const f32x4*)&b2[dbase + 4];
        f32x4 w0 = *(const f32x4*)&W3[dbase], w1 = *(const f32x4*)&W3[dbase + 4];
        float v = 0.0f;
        #pragma unroll
        for (int j = 0; j < 4; ++j) {
            v += fmaxf(a[j] + v0[j], 0.0f) * w0[j];
            v += fmaxf(a[j + 4] + v1[j], 0.0f) * w1[j];
        }
        v += __shfl_xor(v, 1, 64);
        v += __shfl_xor(v, 2, 64);
        v += __shfl_xor(v, 4, 64);
        if ((lane & 7) == 0) tv[c] = v;
    }
    __syncthreads();

    // ---- SpMM3: slog[col] = (S @ tv)[col] + b3   (2 threads per rank)
    {
        int rk = t >> 1, hh = t & 1;
        int e0 = sptr[rk], e1 = sptr[rk + 1];
        int mid = (e0 + e1) >> 1;
        int ea = hh ? mid : e0;
        int eb = hh ? e1 : mid;
        float acc = 0.0f;
        for (int e = ea; e < eb; ++e) {
            unsigned pe = (unsigned)epkg[e];
            float nf = (float)__builtin_bit_cast(hlf2, pe)[0];
            acc = fmaf(nf, *(const float*)((const char*)tv + (pe >> 21)), acc);
        }
        acc += __shfl_xor(acc, 1, 64);
        if (!hh) slog[cmap[rk]] = acc + b3[0];
    }
    __syncthreads();

    // ---- softmax stats over [0, MAIN)
    if (t < 64) {
        float v = (t < MAIN) ? slog[t] : -1e30f;
        float m = v;
        m = fmaxf(m, __shfl_xor(m, 1, 64));
        m = fmaxf(m, __shfl_xor(m, 2, 64));
        m = fmaxf(m, __shfl_xor(m, 4, 64));
        m = fmaxf(m, __shfl_xor(m, 8, 64));
        float ev = (t < MAIN) ? __expf(v - m) : 0.0f;
        ev += __shfl_xor(ev, 1, 64);
        ev += __shfl_xor(ev, 2, 64);
        ev += __shfl_xor(ev, 4, 64);
        ev += __shfl_xor(ev, 8, 64);
        if (t == 0) { sred[0] = m; sred[1] = ev; }
    }
    __syncthreads();

    if (t < NUM) {
        float l = slog[t];
        float o = (t < MAIN) ? __expf(l - sred[0]) / sred[1]
                             : 1.0f / (1.0f + __expf(-l));
        out[b * NUM + t] = o;
    }
#undef MACROW
}

// ---------------------------------------------------------------------------
extern "C" void kernel_launch(void* const* d_in, const int* in_sizes, int n_in,
                              void* d_out, int out_size, void* d_ws, size_t ws_size,
                              hipStream_t stream) {
    const float* x    = (const float*)d_in[0];
    const float* emb  = (const float*)d_in[1];
    const float* W1   = (const float*)d_in[2];
    const float* b1   = (const float*)d_in[3];
    const float* W2   = (const float*)d_in[4];
    const float* b2   = (const float*)d_in[5];
    const float* W3   = (const float*)d_in[6];
    const float* b3   = (const float*)d_in[7];
    const int*   erow = (const int*)d_in[8];
    const int*   ecol = (const int*)d_in[9];

    char* ws = (char*)d_ws;
    int*   rsptr  = (int*)ws;                // 513 ints  [0, 2052)
    int*   colmap = (int*)(ws + 2176);       // 512 ints  [2176, 4224)
    int*   epk    = (int*)(ws + 4224);       // 4608 ints [4224, 22656)
    short* E1     = (short*)(ws + 22656);    // 32768 f16 [22656, 88192)
    short* W2T    = (short*)(ws + 88192);    // 4096 f16  [88192, 96384)

    prep_all<<<73, 512, 0, stream>>>(erow, ecol, emb, W1, W2,
                                     rsptr, colmap, epk, E1, W2T);
    gcn_body<<<NB, 1024, 0, stream>>>(x, (const hlf*)E1, (const hlf*)W2T,
                                      b1, b2, W3, b3,
                                      rsptr, colmap, epk, (float*)d_out);
}

// Round 13
// 174.780 us; speedup vs baseline: 1.1211x; 1.0446x over previous
//
#include <hip/hip_runtime.h>
#include <stdint.h>

#define NB    1024   // batch
#define NUM   512    // nodes
#define HD    64     // hidden dim
#define NE    4096   // edges
#define NEP   4608   // padded edge capacity (each column padded to even count)
#define MAIN  10     // softmax segment

typedef _Float16 hlf;
typedef __attribute__((ext_vector_type(2))) _Float16 hlf2;
typedef __attribute__((ext_vector_type(8))) _Float16 hlf8;
typedef __attribute__((ext_vector_type(4))) float f32x4;

__device__ __forceinline__ unsigned short f2h(float f) {
    hlf v = (hlf)f;
    return __builtin_bit_cast(unsigned short, v);
}

// ---------------------------------------------------------------------------
// Prep (identical to the proven R6 kernel): block 0 builds degree-sorted,
// even-padded CSR via wave-shfl scans; blocks 1..72 cast E1 = emb@W1 and
// W2T = W2^T to f16. Edge pack: epk = (row << 23) | f16(norm).
// ---------------------------------------------------------------------------
__global__ __launch_bounds__(512) void prep_all(
    const int* __restrict__ erow, const int* __restrict__ ecol,
    const float* __restrict__ emb, const float* __restrict__ W1,
    const float* __restrict__ W2,
    int* __restrict__ rsptr, int* __restrict__ colmap, int* __restrict__ epk,
    short* __restrict__ E1, short* __restrict__ W2T)
{
    const int t = threadIdx.x;
    if (blockIdx.x != 0) {
        int g = (blockIdx.x - 1) * 512 + t;     // 72 x 512 = 36864
        if (g < NUM * HD) {
            int node = g >> 6, dim = g & 63;
            float acc = 0.0f;
            #pragma unroll
            for (int k = 0; k < HD; ++k) acc += emb[node * HD + k] * W1[k * HD + dim];
            E1[g] = (short)f2h(acc);
        } else if (g < NUM * HD + HD * HD) {
            int j = g - NUM * HD;
            int dout = j >> 6, din = j & 63;
            W2T[j] = (short)f2h(W2[din * HD + dout]);
        }
        return;
    }

    __shared__ int   sdeg[NUM];
    __shared__ int   aux[NUM];
    __shared__ float sdv[NUM];
    __shared__ int   rnk[NUM];
    __shared__ int   rdg[NUM];
    __shared__ int   wsum[8];

    const int lane = t & 63, wv = t >> 6;

    sdeg[t] = 0; aux[t] = 0;
    __syncthreads();
    for (int e = t; e < NE; e += 512) atomicAdd(&sdeg[ecol[e]], 1);
    __syncthreads();
    const int deg  = sdeg[t];
    const int pdeg = (deg + 1) & ~1;            // pad to even
    const int dbin = deg < NUM ? deg : NUM - 1;
    sdv[t] = deg > 0 ? rsqrtf((float)deg) : 0.0f;
    atomicAdd(&aux[dbin], 1);
    __syncthreads();
    {
        int v = aux[t];
        #pragma unroll
        for (int ofs = 1; ofs < 64; ofs <<= 1) {
            int sh = __shfl_up(v, ofs, 64);
            if (lane >= ofs) v += sh;
        }
        if (lane == 63) wsum[wv] = v;
        __syncthreads();
        if (t == 0) {
            int s = 0;
            #pragma unroll
            for (int w = 0; w < 8; ++w) { int tmp = wsum[w]; wsum[w] = s; s += tmp; }
        }
        __syncthreads();
        int inc = v + wsum[wv];
        aux[t]  = inc;
        __syncthreads();
        sdeg[t] = (t == 0) ? 0 : aux[t - 1];
        __syncthreads();
    }
    {
        int r = atomicAdd(&sdeg[dbin], 1);      // degree-sorted rank
        rnk[t] = r;
        rdg[r] = pdeg;
        colmap[r] = t;
    }
    __syncthreads();
    {
        int dv = rdg[t], v = dv;
        #pragma unroll
        for (int ofs = 1; ofs < 64; ofs <<= 1) {
            int sh = __shfl_up(v, ofs, 64);
            if (lane >= ofs) v += sh;
        }
        if (lane == 63) wsum[wv] = v;
        __syncthreads();
        if (t == 0) {
            int s = 0;
            #pragma unroll
            for (int w = 0; w < 8; ++w) { int tmp = wsum[w]; wsum[w] = s; s += tmp; }
        }
        __syncthreads();
        int inc  = v + wsum[wv];
        int excl = inc - dv;
        rsptr[t] = excl;
        if (t == NUM - 1) rsptr[NUM] = inc;
        aux[t] = excl;
        __syncthreads();
    }
    sdeg[t] = aux[rnk[t]];
    __syncthreads();
    for (int i = t; i < NEP; i += 512) epk[i] = 0;
    __syncthreads();
    for (int e = t; e < NE; e += 512) {
        int c = ecol[e], rr = erow[e];
        int p = atomicAdd(&sdeg[c], 1);
        unsigned ns = (unsigned)f2h(sdv[rr] * sdv[c]);
        epk[p] = (rr << 23) | (int)ns;          // hi16 = row*128
    }
}

// ---------------------------------------------------------------------------
// Body: one block (1024 thr, 16 waves) per BATCH PAIR (b0=2*blk, b0+1).
// R6's lean all-LDS structure with pair-rows: every edge-chain traversal
// serves TWO batch elements (16-lane groups gather 256B pair-rows; per-edge
// addressing amortized over 16 lanes). Single 128 KB H buffer, in-place
// B1pair -> h1pair -> gpair with packed register holds across barriers.
//   SpMM1: h1 = relu(S@B1 + b1)   (8 sets x 64 ranks, 16-lane groups)
//   MFMA : g = h1@W2              (1024x64 @ 64x64, 32 MFMA/wave)
//   SpMM2: tv[bsel][c] = sum_d relu((S@g)+b2).W3
//   SpMM3: logits = S@tv + b3; softmax/sigmoid per element.
// ---------------------------------------------------------------------------
__global__ __launch_bounds__(1024, 4) void gcn_body(
    const float* __restrict__ x, const hlf* __restrict__ E1,
    const hlf* __restrict__ W2T,
    const float* __restrict__ b1, const float* __restrict__ b2,
    const float* __restrict__ W3, const float* __restrict__ b3,
    const int* __restrict__ rsptrg, const int* __restrict__ colmapg,
    const int* __restrict__ epkg,
    float* __restrict__ out)
{
    __shared__ hlf   H[NUM * 128];     // 131072 B: B1pair/h1pair/gpair; slog overlay
    __shared__ int   eps[NEP];         // 18432 B
    __shared__ int   sptr[513];
    __shared__ int   cmap[NUM];
    __shared__ float xs[2 * NUM];      // x-pair, then tv-pair
    __shared__ float sred[4];

    float* slog = (float*)H;           // 2x512 logits after SpMM2

    const int t    = threadIdx.x;
    const int b0   = blockIdx.x * 2;
    const int lane = t & 63;
    const int wave = t >> 6;           // 0..15
    const int q    = lane >> 4;        // 0..3
    const int l15  = lane & 15;
    const int gid  = t >> 4;           // 0..63: 16-lane group
    const int j16  = t & 15;           // lane within group
    const int bsel = j16 >> 3;         // batch half served by this lane
    const int d8   = (j16 & 7) * 8;    // dim strip within the half

    // ---- stage edges + csr + x-pair
    {
        const int4* g4 = (const int4*)epkg;
        *(int4*)&eps[t * 4] = g4[t];                       // 4096 ints
        if (t < 128) *(int4*)&eps[4096 + t * 4] = g4[1024 + t];
    }
    if (t < 513) sptr[t] = rsptrg[t];
    if (t < NUM) cmap[t] = colmapg[t];
    xs[t] = x[b0 * NUM + t];           // rows b0 and b0+1, contiguous
    __syncthreads();

    // ---- build H = B1-pair: H[node][bs*64+d] = x[bs][node] * E1[node][d]
    #pragma unroll
    for (int p = 0; p < 8; ++p) {
        int i = t + p * 1024;          // 8192 chunks of 8 halfs
        int node = i >> 4, sub = i & 15;
        int bs = sub >> 3, dd = (sub & 7) * 8;
        hlf  xh = (hlf)xs[bs * NUM + node];
        hlf8 e  = *(const hlf8*)&E1[node * HD + dd];
        hlf8 o;
        #pragma unroll
        for (int j = 0; j < 8; ++j) o[j] = e[j] * xh;
        *(hlf8*)((char*)H + node * 256 + bs * 128 + dd * 2) = o;
    }
    const char* Hb = (const char*)H + j16 * 16;   // per-lane gather base
    __syncthreads();

// 8 f16->f32 mixed FMAs into acc; norm is the low f16 half of pe
#define MACROW(acc, hv, pe) {                                                 \
        const hlf nh = __builtin_bit_cast(hlf2, (unsigned)(pe))[0];           \
        const hlf2 p0 = __builtin_bit_cast(hlf2, (hv).x);                     \
        const hlf2 p1 = __builtin_bit_cast(hlf2, (hv).y);                     \
        const hlf2 p2 = __builtin_bit_cast(hlf2, (hv).z);                     \
        const hlf2 p3 = __builtin_bit_cast(hlf2, (hv).w);                     \
        acc[0] = fmaf((float)p0[0], (float)nh, acc[0]);                       \
        acc[1] = fmaf((float)p0[1], (float)nh, acc[1]);                       \
        acc[2] = fmaf((float)p1[0], (float)nh, acc[2]);                       \
        acc[3] = fmaf((float)p1[1], (float)nh, acc[3]);                       \
        acc[4] = fmaf((float)p2[0], (float)nh, acc[4]);                       \
        acc[5] = fmaf((float)p2[1], (float)nh, acc[5]);                       \
        acc[6] = fmaf((float)p3[0], (float)nh, acc[6]);                       \
        acc[7] = fmaf((float)p3[1], (float)nh, acc[7]); }

// pair-row byte offset: hi16(pe) = row*128 -> *2 = row*256
#define LDROWP(d, pe) d = *(const uint4*)(Hb + (((unsigned)(pe) >> 16) << 1));

    // ---- SpMM1: h1 = relu(S@B1 + b1); hold packed, write in-place post-barrier
    {
        uint4 hv[8];
        #pragma unroll 1
        for (int set = 0; set < 8; ++set) {
            int r  = set * 64 + gid;
            int e0 = sptr[r], e1 = sptr[r + 1];
            float a[8];
            #pragma unroll
            for (int j = 0; j < 8; ++j) a[j] = 0.0f;
            for (int e = e0; e < e1; e += 2) {     // even-padded: exact
                int2 qa = *(const int2*)&eps[e];
                uint4 c0, c1;
                LDROWP(c0, qa.x) LDROWP(c1, qa.y)
                MACROW(a, c0, qa.x) MACROW(a, c1, qa.y)
            }
            f32x4 u0 = *(const f32x4*)&b1[d8];
            f32x4 u1 = *(const f32x4*)&b1[d8 + 4];
            hv[set].x = __builtin_bit_cast(unsigned, __builtin_amdgcn_cvt_pkrtz(
                            fmaxf(a[0] + u0[0], 0.0f), fmaxf(a[1] + u0[1], 0.0f)));
            hv[set].y = __builtin_bit_cast(unsigned, __builtin_amdgcn_cvt_pkrtz(
                            fmaxf(a[2] + u0[2], 0.0f), fmaxf(a[3] + u0[3], 0.0f)));
            hv[set].z = __builtin_bit_cast(unsigned, __builtin_amdgcn_cvt_pkrtz(
                            fmaxf(a[4] + u1[0], 0.0f), fmaxf(a[5] + u1[1], 0.0f)));
            hv[set].w = __builtin_bit_cast(unsigned, __builtin_amdgcn_cvt_pkrtz(
                            fmaxf(a[6] + u1[2], 0.0f), fmaxf(a[7] + u1[3], 0.0f)));
        }
        __syncthreads();   // all B1 gathers complete
        #pragma unroll
        for (int set = 0; set < 8; ++set) {
            int r = set * 64 + gid;
            *(uint4*)((char*)H + cmap[r] * 256 + bsel * 128 + d8 * 2) = hv[set];
        }
    }
    __syncthreads();

    // ---- MFMA: g = h1 @ W2 (H viewed as 1024x64 f16, row = node*2+bsel)
    {
        uint2 gk[4][4];
        #pragma unroll 1
        for (int mm = 0; mm < 4; ++mm) {
            int m = wave * 64 + mm * 16 + l15;
            hlf8 a0 = *(const hlf8*)((const char*)H + m * 128 + q * 16);
            hlf8 a1 = *(const hlf8*)((const char*)H + m * 128 + 64 + q * 16);
            #pragma unroll
            for (int nt = 0; nt < 4; ++nt) {
                hlf8 w0 = *(const hlf8*)&W2T[(nt * 16 + l15) * HD + q * 8];
                hlf8 w1 = *(const hlf8*)&W2T[(nt * 16 + l15) * HD + 32 + q * 8];
                f32x4 acc = (f32x4){0.f, 0.f, 0.f, 0.f};
                acc = __builtin_amdgcn_mfma_f32_16x16x32_f16(a0, w0, acc, 0, 0, 0);
                acc = __builtin_amdgcn_mfma_f32_16x16x32_f16(a1, w1, acc, 0, 0, 0);
                gk[mm][nt].x = __builtin_bit_cast(unsigned,
                                   __builtin_amdgcn_cvt_pkrtz(acc[0], acc[1]));
                gk[mm][nt].y = __builtin_bit_cast(unsigned,
                                   __builtin_amdgcn_cvt_pkrtz(acc[2], acc[3]));
            }
        }
        __syncthreads();   // all h1 reads complete
        #pragma unroll
        for (int mm = 0; mm < 4; ++mm)
            #pragma unroll
            for (int nt = 0; nt < 4; ++nt) {
                int mrow = wave * 64 + mm * 16 + q * 4;
                hlf2 lo = __builtin_bit_cast(hlf2, gk[mm][nt].x);
                hlf2 hi = __builtin_bit_cast(hlf2, gk[mm][nt].y);
                H[(mrow + 0) * HD + nt * 16 + l15] = lo[0];
                H[(mrow + 1) * HD + nt * 16 + l15] = lo[1];
                H[(mrow + 2) * HD + nt * 16 + l15] = hi[0];
                H[(mrow + 3) * HD + nt * 16 + l15] = hi[1];
            }
    }
    __syncthreads();

    // ---- SpMM2 + epilogue: tv[bsel][c] = sum_d relu((S@g)[c,d]+b2[d])*W3[d]
    #pragma unroll 1
    for (int set = 0; set < 8; ++set) {
        int r  = set * 64 + gid;
        int e0 = sptr[r], e1 = sptr[r + 1];
        int c  = cmap[r];
        float a[8];
        #pragma unroll
        for (int j = 0; j < 8; ++j) a[j] = 0.0f;
        int e = e0;
        for (; e + 4 <= e1; e += 4) {
            int2 qa = *(const int2*)&eps[e];
            int2 qb = *(const int2*)&eps[e + 2];
            uint4 c0, c1, c2, c3;
            LDROWP(c0, qa.x) LDROWP(c1, qa.y) LDROWP(c2, qb.x) LDROWP(c3, qb.y)
            MACROW(a, c0, qa.x) MACROW(a, c1, qa.y)
            MACROW(a, c2, qb.x) MACROW(a, c3, qb.y)
        }
        if (e < e1) {
            int2 qa = *(const int2*)&eps[e];
            uint4 c0, c1;
            LDROWP(c0, qa.x) LDROWP(c1, qa.y)
            MACROW(a, c0, qa.x) MACROW(a, c1, qa.y)
        }
        f32x4 v0 = *(const f32x4*)&b2[d8], v1 = *(const f32x4*)&b2[d8 + 4];
        f32x4 w0 = *(const f32x4*)&W3[d8], w1 = *(const f32x4*)&W3[d8 + 4];
        float v = 0.0f;
        #pragma unroll
        for (int j = 0; j < 4; ++j) {
            v += fmaxf(a[j] + v0[j], 0.0f) * w0[j];
            v += fmaxf(a[j + 4] + v1[j], 0.0f) * w1[j];
        }
        v += __shfl_xor(v, 1, 64);
        v += __shfl_xor(v, 2, 64);
        v += __shfl_xor(v, 4, 64);
        if ((t & 7) == 0) xs[bsel * NUM + c] = v;   // xs now tv-pair
    }
    __syncthreads();

    // ---- SpMM3: logits = S@tv + b3  (one (rank, batch-half) per thread)
    {
        int bs = t >> 9, rk = t & 511;
        int e0 = sptr[rk], e1 = sptr[rk + 1];
        const float* TVB = xs + bs * NUM;
        float acc = 0.0f;
        for (int e = e0; e < e1; ++e) {
            unsigned pe = (unsigned)eps[e];
            float nf = (float)__builtin_bit_cast(hlf2, pe)[0];
            acc = fmaf(nf, TVB[pe >> 23], acc);
        }
        slog[bs * NUM + cmap[rk]] = acc + b3[0];
    }
    __syncthreads();

    // ---- softmax stats over [0, MAIN) for each element
    if (t < 128) {
        int bs = t >> 6, l = t & 63;
        float v = (l < MAIN) ? slog[bs * NUM + l] : -1e30f;
        float m = v;
        m = fmaxf(m, __shfl_xor(m, 1, 64));
        m = fmaxf(m, __shfl_xor(m, 2, 64));
        m = fmaxf(m, __shfl_xor(m, 4, 64));
        m = fmaxf(m, __shfl_xor(m, 8, 64));
        float ev = (l < MAIN) ? __expf(v - m) : 0.0f;
        ev += __shfl_xor(ev, 1, 64);
        ev += __shfl_xor(ev, 2, 64);
        ev += __shfl_xor(ev, 4, 64);
        ev += __shfl_xor(ev, 8, 64);
        if (l == 0) { sred[bs * 2] = m; sred[bs * 2 + 1] = ev; }
    }
    __syncthreads();

    {
        int bs = t >> 9, rk = t & 511;
        float l = slog[bs * NUM + rk];
        float o = (rk < MAIN) ? __expf(l - sred[bs * 2]) / sred[bs * 2 + 1]
                              : 1.0f / (1.0f + __expf(-l));
        out[(b0 + bs) * NUM + rk] = o;
    }
#undef MACROW
#undef LDROWP
}

// ---------------------------------------------------------------------------
extern "C" void kernel_launch(void* const* d_in, const int* in_sizes, int n_in,
                              void* d_out, int out_size, void* d_ws, size_t ws_size,
                              hipStream_t stream) {
    const float* x    = (const float*)d_in[0];
    const float* emb  = (const float*)d_in[1];
    const float* W1   = (const float*)d_in[2];
    const float* b1   = (const float*)d_in[3];
    const float* W2   = (const float*)d_in[4];
    const float* b2   = (const float*)d_in[5];
    const float* W3   = (const float*)d_in[6];
    const float* b3   = (const float*)d_in[7];
    const int*   erow = (const int*)d_in[8];
    const int*   ecol = (const int*)d_in[9];

    char* ws = (char*)d_ws;
    int*   rsptr  = (int*)ws;                // 513 ints  [0, 2052)
    int*   colmap = (int*)(ws + 2176);       // 512 ints  [2176, 4224)
    int*   epk    = (int*)(ws + 4224);       // 4608 ints [4224, 22656)
    short* E1     = (short*)(ws + 22656);    // 32768 f16 [22656, 88192)
    short* W2T    = (short*)(ws + 88192);    // 4096 f16  [88192, 96384)

    prep_all<<<73, 512, 0, stream>>>(erow, ecol, emb, W1, W2,
                                     rsptr, colmap, epk, E1, W2T);
    gcn_body<<<NB / 2, 1024, 0, stream>>>(x, (const hlf*)E1, (const hlf*)W2T,
                                          b1, b2, W3, b3,
                                          rsptr, colmap, epk, (float*)d_out);
}

// Round 14
// 149.450 us; speedup vs baseline: 1.3111x; 1.1695x over previous
//
#include <hip/hip_runtime.h>
#include <stdint.h>

#define NB    1024   // batch
#define NUM   512    // nodes
#define HD    64     // hidden dim
#define NE    4096   // edges
#define NEP   4608   // padded edge capacity (each column padded to even count)
#define MAIN  10     // softmax segment

typedef _Float16 hlf;
typedef __attribute__((ext_vector_type(2))) _Float16 hlf2;
typedef __attribute__((ext_vector_type(8))) _Float16 hlf8;
typedef __attribute__((ext_vector_type(4))) float f32x4;

__device__ __forceinline__ unsigned short f2h(float f) {
    hlf v = (hlf)f;
    return __builtin_bit_cast(unsigned short, v);
}

// ---------------------------------------------------------------------------
// Prep (identical to the proven R6 kernel): block 0 builds degree-sorted,
// even-padded CSR via wave-shfl scans; blocks 1..72 cast E1 = emb@W1 and
// W2T = W2^T to f16. Edge pack: epk = (row << 23) | f16(norm).
// ---------------------------------------------------------------------------
__global__ __launch_bounds__(512) void prep_all(
    const int* __restrict__ erow, const int* __restrict__ ecol,
    const float* __restrict__ emb, const float* __restrict__ W1,
    const float* __restrict__ W2,
    int* __restrict__ rsptr, int* __restrict__ colmap, int* __restrict__ epk,
    short* __restrict__ E1, short* __restrict__ W2T)
{
    const int t = threadIdx.x;
    if (blockIdx.x != 0) {
        int g = (blockIdx.x - 1) * 512 + t;     // 72 x 512 = 36864
        if (g < NUM * HD) {
            int node = g >> 6, dim = g & 63;
            float acc = 0.0f;
            #pragma unroll
            for (int k = 0; k < HD; ++k) acc += emb[node * HD + k] * W1[k * HD + dim];
            E1[g] = (short)f2h(acc);
        } else if (g < NUM * HD + HD * HD) {
            int j = g - NUM * HD;
            int dout = j >> 6, din = j & 63;
            W2T[j] = (short)f2h(W2[din * HD + dout]);
        }
        return;
    }

    __shared__ int   sdeg[NUM];
    __shared__ int   aux[NUM];
    __shared__ float sdv[NUM];
    __shared__ int   rnk[NUM];
    __shared__ int   rdg[NUM];
    __shared__ int   wsum[8];

    const int lane = t & 63, wv = t >> 6;

    sdeg[t] = 0; aux[t] = 0;
    __syncthreads();
    for (int e = t; e < NE; e += 512) atomicAdd(&sdeg[ecol[e]], 1);
    __syncthreads();
    const int deg  = sdeg[t];
    const int pdeg = (deg + 1) & ~1;            // pad to even
    const int dbin = deg < NUM ? deg : NUM - 1;
    sdv[t] = deg > 0 ? rsqrtf((float)deg) : 0.0f;
    atomicAdd(&aux[dbin], 1);
    __syncthreads();
    {
        int v = aux[t];
        #pragma unroll
        for (int ofs = 1; ofs < 64; ofs <<= 1) {
            int sh = __shfl_up(v, ofs, 64);
            if (lane >= ofs) v += sh;
        }
        if (lane == 63) wsum[wv] = v;
        __syncthreads();
        if (t == 0) {
            int s = 0;
            #pragma unroll
            for (int w = 0; w < 8; ++w) { int tmp = wsum[w]; wsum[w] = s; s += tmp; }
        }
        __syncthreads();
        int inc = v + wsum[wv];
        aux[t]  = inc;
        __syncthreads();
        sdeg[t] = (t == 0) ? 0 : aux[t - 1];
        __syncthreads();
    }
    {
        int r = atomicAdd(&sdeg[dbin], 1);      // degree-sorted rank
        rnk[t] = r;
        rdg[r] = pdeg;
        colmap[r] = t;
    }
    __syncthreads();
    {
        int dv = rdg[t], v = dv;
        #pragma unroll
        for (int ofs = 1; ofs < 64; ofs <<= 1) {
            int sh = __shfl_up(v, ofs, 64);
            if (lane >= ofs) v += sh;
        }
        if (lane == 63) wsum[wv] = v;
        __syncthreads();
        if (t == 0) {
            int s = 0;
            #pragma unroll
            for (int w = 0; w < 8; ++w) { int tmp = wsum[w]; wsum[w] = s; s += tmp; }
        }
        __syncthreads();
        int inc  = v + wsum[wv];
        int excl = inc - dv;
        rsptr[t] = excl;
        if (t == NUM - 1) rsptr[NUM] = inc;
        aux[t] = excl;
        __syncthreads();
    }
    sdeg[t] = aux[rnk[t]];
    __syncthreads();
    for (int i = t; i < NEP; i += 512) epk[i] = 0;
    __syncthreads();
    for (int e = t; e < NE; e += 512) {
        int c = ecol[e], rr = erow[e];
        int p = atomicAdd(&sdeg[c], 1);
        unsigned ns = (unsigned)f2h(sdv[rr] * sdv[c]);
        epk[p] = (rr << 23) | (int)ns;          // hi16 = row*128
    }
}

// ---------------------------------------------------------------------------
// Body: one block (1024 thr, 16 waves) per BATCH PAIR (b0=2*blk, b0+1).
// R6's lean all-LDS structure with pair-rows: every edge-chain traversal
// serves TWO batch elements. Hold arrays are indexed ONLY by compile-time
// constants (fully unrolled loops) so they stay in registers (rule #20).
// ---------------------------------------------------------------------------
__global__ __launch_bounds__(1024, 4) void gcn_body(
    const float* __restrict__ x, const hlf* __restrict__ E1,
    const hlf* __restrict__ W2T,
    const float* __restrict__ b1, const float* __restrict__ b2,
    const float* __restrict__ W3, const float* __restrict__ b3,
    const int* __restrict__ rsptrg, const int* __restrict__ colmapg,
    const int* __restrict__ epkg,
    float* __restrict__ out)
{
    __shared__ hlf   H[NUM * 128];     // 131072 B: B1pair/h1pair/gpair; slog overlay
    __shared__ int   eps[NEP];         // 18432 B
    __shared__ int   sptr[513];
    __shared__ int   cmap[NUM];
    __shared__ float xs[2 * NUM];      // x-pair, then tv-pair
    __shared__ float sred[4];

    float* slog = (float*)H;           // 2x512 logits after SpMM2

    const int t    = threadIdx.x;
    const int b0   = blockIdx.x * 2;
    const int lane = t & 63;
    const int wave = t >> 6;           // 0..15
    const int q    = lane >> 4;        // 0..3
    const int l15  = lane & 15;
    const int gid  = t >> 4;           // 0..63: 16-lane group
    const int j16  = t & 15;           // lane within group
    const int bsel = j16 >> 3;         // batch half served by this lane
    const int d8   = (j16 & 7) * 8;    // dim strip within the half

    // ---- stage edges + csr + x-pair
    {
        const int4* g4 = (const int4*)epkg;
        *(int4*)&eps[t * 4] = g4[t];                       // 4096 ints
        if (t < 128) *(int4*)&eps[4096 + t * 4] = g4[1024 + t];
    }
    if (t < 513) sptr[t] = rsptrg[t];
    if (t < NUM) cmap[t] = colmapg[t];
    xs[t] = x[b0 * NUM + t];           // rows b0 and b0+1, contiguous
    __syncthreads();

    // ---- build H = B1-pair: H[node][bs*64+d] = x[bs][node] * E1[node][d]
    #pragma unroll
    for (int p = 0; p < 8; ++p) {
        int i = t + p * 1024;          // 8192 chunks of 8 halfs
        int node = i >> 4, sub = i & 15;
        int bs = sub >> 3, dd = (sub & 7) * 8;
        hlf  xh = (hlf)xs[bs * NUM + node];
        hlf8 e  = *(const hlf8*)&E1[node * HD + dd];
        hlf8 o;
        #pragma unroll
        for (int j = 0; j < 8; ++j) o[j] = e[j] * xh;
        *(hlf8*)((char*)H + node * 256 + bs * 128 + dd * 2) = o;
    }
    const char* Hb = (const char*)H + j16 * 16;   // per-lane gather base
    __syncthreads();

// 8 f16->f32 mixed FMAs into acc; norm is the low f16 half of pe
#define MACROW(acc, hv, pe) {                                                 \
        const hlf nh = __builtin_bit_cast(hlf2, (unsigned)(pe))[0];           \
        const hlf2 p0 = __builtin_bit_cast(hlf2, (hv).x);                     \
        const hlf2 p1 = __builtin_bit_cast(hlf2, (hv).y);                     \
        const hlf2 p2 = __builtin_bit_cast(hlf2, (hv).z);                     \
        const hlf2 p3 = __builtin_bit_cast(hlf2, (hv).w);                     \
        acc[0] = fmaf((float)p0[0], (float)nh, acc[0]);                       \
        acc[1] = fmaf((float)p0[1], (float)nh, acc[1]);                       \
        acc[2] = fmaf((float)p1[0], (float)nh, acc[2]);                       \
        acc[3] = fmaf((float)p1[1], (float)nh, acc[3]);                       \
        acc[4] = fmaf((float)p2[0], (float)nh, acc[4]);                       \
        acc[5] = fmaf((float)p2[1], (float)nh, acc[5]);                       \
        acc[6] = fmaf((float)p3[0], (float)nh, acc[6]);                       \
        acc[7] = fmaf((float)p3[1], (float)nh, acc[7]); }

// pair-row byte offset: hi16(pe) = row*128 -> *2 = row*256
#define LDROWP(d, pe) d = *(const uint4*)(Hb + (((unsigned)(pe) >> 16) << 1));

// one SpMM1 rank: accumulate, bias+relu, pack into the named hold HV
#define SPMM1_SET(SET, HV) {                                                  \
        int r  = (SET) * 64 + gid;                                            \
        int e0 = sptr[r], e1 = sptr[r + 1];                                   \
        float a[8];                                                           \
        _Pragma("unroll")                                                     \
        for (int j = 0; j < 8; ++j) a[j] = 0.0f;                              \
        for (int e = e0; e < e1; e += 2) {                                    \
            int2 qa = *(const int2*)&eps[e];                                  \
            uint4 c0, c1;                                                     \
            LDROWP(c0, qa.x) LDROWP(c1, qa.y)                                 \
            MACROW(a, c0, qa.x) MACROW(a, c1, qa.y)                           \
        }                                                                     \
        f32x4 u0 = *(const f32x4*)&b1[d8];                                    \
        f32x4 u1 = *(const f32x4*)&b1[d8 + 4];                                \
        HV.x = __builtin_bit_cast(unsigned, __builtin_amdgcn_cvt_pkrtz(       \
                   fmaxf(a[0] + u0[0], 0.0f), fmaxf(a[1] + u0[1], 0.0f)));    \
        HV.y = __builtin_bit_cast(unsigned, __builtin_amdgcn_cvt_pkrtz(       \
                   fmaxf(a[2] + u0[2], 0.0f), fmaxf(a[3] + u0[3], 0.0f)));    \
        HV.z = __builtin_bit_cast(unsigned, __builtin_amdgcn_cvt_pkrtz(       \
                   fmaxf(a[4] + u1[0], 0.0f), fmaxf(a[5] + u1[1], 0.0f)));    \
        HV.w = __builtin_bit_cast(unsigned, __builtin_amdgcn_cvt_pkrtz(       \
                   fmaxf(a[6] + u1[2], 0.0f), fmaxf(a[7] + u1[3], 0.0f)));    }

#define SPMM1_WB(SET, HV) {                                                   \
        int r = (SET) * 64 + gid;                                             \
        *(uint4*)((char*)H + cmap[r] * 256 + bsel * 128 + d8 * 2) = HV;       }

    // ---- SpMM1: h1 = relu(S@B1 + b1); named register holds, in-place write
    {
        uint4 hv0, hv1, hv2, hv3, hv4, hv5, hv6, hv7;
        SPMM1_SET(0, hv0) SPMM1_SET(1, hv1) SPMM1_SET(2, hv2) SPMM1_SET(3, hv3)
        SPMM1_SET(4, hv4) SPMM1_SET(5, hv5) SPMM1_SET(6, hv6) SPMM1_SET(7, hv7)
        __syncthreads();   // all B1 gathers complete
        SPMM1_WB(0, hv0) SPMM1_WB(1, hv1) SPMM1_WB(2, hv2) SPMM1_WB(3, hv3)
        SPMM1_WB(4, hv4) SPMM1_WB(5, hv5) SPMM1_WB(6, hv6) SPMM1_WB(7, hv7)
    }
    __syncthreads();

    // ---- MFMA: g = h1 @ W2 (H viewed as 1024x64 f16, row = node*2+bsel)
    {
        uint2 gk[4][4];
        #pragma unroll
        for (int mm = 0; mm < 4; ++mm) {
            int m = wave * 64 + mm * 16 + l15;
            hlf8 a0 = *(const hlf8*)((const char*)H + m * 128 + q * 16);
            hlf8 a1 = *(const hlf8*)((const char*)H + m * 128 + 64 + q * 16);
            #pragma unroll
            for (int nt = 0; nt < 4; ++nt) {
                hlf8 w0 = *(const hlf8*)&W2T[(nt * 16 + l15) * HD + q * 8];
                hlf8 w1 = *(const hlf8*)&W2T[(nt * 16 + l15) * HD + 32 + q * 8];
                f32x4 acc = (f32x4){0.f, 0.f, 0.f, 0.f};
                acc = __builtin_amdgcn_mfma_f32_16x16x32_f16(a0, w0, acc, 0, 0, 0);
                acc = __builtin_amdgcn_mfma_f32_16x16x32_f16(a1, w1, acc, 0, 0, 0);
                gk[mm][nt].x = __builtin_bit_cast(unsigned,
                                   __builtin_amdgcn_cvt_pkrtz(acc[0], acc[1]));
                gk[mm][nt].y = __builtin_bit_cast(unsigned,
                                   __builtin_amdgcn_cvt_pkrtz(acc[2], acc[3]));
            }
        }
        __syncthreads();   // all h1 reads complete
        #pragma unroll
        for (int mm = 0; mm < 4; ++mm)
            #pragma unroll
            for (int nt = 0; nt < 4; ++nt) {
                int mrow = wave * 64 + mm * 16 + q * 4;
                hlf2 lo = __builtin_bit_cast(hlf2, gk[mm][nt].x);
                hlf2 hi = __builtin_bit_cast(hlf2, gk[mm][nt].y);
                H[(mrow + 0) * HD + nt * 16 + l15] = lo[0];
                H[(mrow + 1) * HD + nt * 16 + l15] = lo[1];
                H[(mrow + 2) * HD + nt * 16 + l15] = hi[0];
                H[(mrow + 3) * HD + nt * 16 + l15] = hi[1];
            }
    }
    __syncthreads();

    // ---- SpMM2 + epilogue: tv[bsel][c] = sum_d relu((S@g)[c,d]+b2[d])*W3[d]
    #pragma unroll 1
    for (int set = 0; set < 8; ++set) {
        int r  = set * 64 + gid;
        int e0 = sptr[r], e1 = sptr[r + 1];
        int c  = cmap[r];
        float a[8];
        #pragma unroll
        for (int j = 0; j < 8; ++j) a[j] = 0.0f;
        int e = e0;
        for (; e + 4 <= e1; e += 4) {
            int2 qa = *(const int2*)&eps[e];
            int2 qb = *(const int2*)&eps[e + 2];
            uint4 c0, c1, c2, c3;
            LDROWP(c0, qa.x) LDROWP(c1, qa.y) LDROWP(c2, qb.x) LDROWP(c3, qb.y)
            MACROW(a, c0, qa.x) MACROW(a, c1, qa.y)
            MACROW(a, c2, qb.x) MACROW(a, c3, qb.y)
        }
        if (e < e1) {
            int2 qa = *(const int2*)&eps[e];
            uint4 c0, c1;
            LDROWP(c0, qa.x) LDROWP(c1, qa.y)
            MACROW(a, c0, qa.x) MACROW(a, c1, qa.y)
        }
        f32x4 v0 = *(const f32x4*)&b2[d8], v1 = *(const f32x4*)&b2[d8 + 4];
        f32x4 w0 = *(const f32x4*)&W3[d8], w1 = *(const f32x4*)&W3[d8 + 4];
        float v = 0.0f;
        #pragma unroll
        for (int j = 0; j < 4; ++j) {
            v += fmaxf(a[j] + v0[j], 0.0f) * w0[j];
            v += fmaxf(a[j + 4] + v1[j], 0.0f) * w1[j];
        }
        v += __shfl_xor(v, 1, 64);
        v += __shfl_xor(v, 2, 64);
        v += __shfl_xor(v, 4, 64);
        if ((t & 7) == 0) xs[bsel * NUM + c] = v;   // xs now tv-pair
    }
    __syncthreads();

    // ---- SpMM3: logits = S@tv + b3  (one (rank, batch-half) per thread)
    {
        int bs = t >> 9, rk = t & 511;
        int e0 = sptr[rk], e1 = sptr[rk + 1];
        const float* TVB = xs + bs * NUM;
        float acc = 0.0f;
        for (int e = e0; e < e1; ++e) {
            unsigned pe = (unsigned)eps[e];
            float nf = (float)__builtin_bit_cast(hlf2, pe)[0];
            acc = fmaf(nf, TVB[pe >> 23], acc);
        }
        slog[bs * NUM + cmap[rk]] = acc + b3[0];
    }
    __syncthreads();

    // ---- softmax stats over [0, MAIN) for each element
    if (t < 128) {
        int bs = t >> 6, l = t & 63;
        float v = (l < MAIN) ? slog[bs * NUM + l] : -1e30f;
        float m = v;
        m = fmaxf(m, __shfl_xor(m, 1, 64));
        m = fmaxf(m, __shfl_xor(m, 2, 64));
        m = fmaxf(m, __shfl_xor(m, 4, 64));
        m = fmaxf(m, __shfl_xor(m, 8, 64));
        float ev = (l < MAIN) ? __expf(v - m) : 0.0f;
        ev += __shfl_xor(ev, 1, 64);
        ev += __shfl_xor(ev, 2, 64);
        ev += __shfl_xor(ev, 4, 64);
        ev += __shfl_xor(ev, 8, 64);
        if (l == 0) { sred[bs * 2] = m; sred[bs * 2 + 1] = ev; }
    }
    __syncthreads();

    {
        int bs = t >> 9, rk = t & 511;
        float l = slog[bs * NUM + rk];
        float o = (rk < MAIN) ? __expf(l - sred[bs * 2]) / sred[bs * 2 + 1]
                              : 1.0f / (1.0f + __expf(-l));
        out[(b0 + bs) * NUM + rk] = o;
    }
#undef MACROW
#undef LDROWP
#undef SPMM1_SET
#undef SPMM1_WB
}

// ---------------------------------------------------------------------------
extern "C" void kernel_launch(void* const* d_in, const int* in_sizes, int n_in,
                              void* d_out, int out_size, void* d_ws, size_t ws_size,
                              hipStream_t stream) {
    const float* x    = (const float*)d_in[0];
    const float* emb  = (const float*)d_in[1];
    const float* W1   = (const float*)d_in[2];
    const float* b1   = (const float*)d_in[3];
    const float* W2   = (const float*)d_in[4];
    const float* b2   = (const float*)d_in[5];
    const float* W3   = (const float*)d_in[6];
    const float* b3   = (const float*)d_in[7];
    const int*   erow = (const int*)d_in[8];
    const int*   ecol = (const int*)d_in[9];

    char* ws = (char*)d_ws;
    int*   rsptr  = (int*)ws;                // 513 ints  [0, 2052)
    int*   colmap = (int*)(ws + 2176);       // 512 ints  [2176, 4224)
    int*   epk    = (int*)(ws + 4224);       // 4608 ints [4224, 22656)
    short* E1     = (short*)(ws + 22656);    // 32768 f16 [22656, 88192)
    short* W2T    = (short*)(ws + 88192);    // 4096 f16  [88192, 96384)

    prep_all<<<73, 512, 0, stream>>>(erow, ecol, emb, W1, W2,
                                     rsptr, colmap, epk, E1, W2T);
    gcn_body<<<NB / 2, 1024, 0, stream>>>(x, (const hlf*)E1, (const hlf*)W2T,
                                          b1, b2, W3, b3,
                                          rsptr, colmap, epk, (float*)d_out);
}

// Round 15
// 141.331 us; speedup vs baseline: 1.3864x; 1.0574x over previous
//
#include <hip/hip_runtime.h>
#include <stdint.h>

#define NB    1024   // batch
#define NUM   512    // nodes
#define HD    64     // hidden dim
#define NE    4096   // edges
#define NEP   4608   // padded edge capacity (each column padded to even count)
#define MAIN  10     // softmax segment

typedef _Float16 hlf;
typedef __attribute__((ext_vector_type(2))) _Float16 hlf2;
typedef __attribute__((ext_vector_type(8))) _Float16 hlf8;
typedef __attribute__((ext_vector_type(4))) float f32x4;

__device__ __forceinline__ unsigned short f2h(float f) {
    hlf v = (hlf)f;
    return __builtin_bit_cast(unsigned short, v);
}

// ---------------------------------------------------------------------------
// Prep (identical to the proven R6/R14 kernel): block 0 builds degree-sorted,
// even-padded CSR via wave-shfl scans; blocks 1..72 cast E1 = emb@W1 and
// W2T = W2^T to f16. Edge pack: epk = (row << 23) | f16(norm).
// ---------------------------------------------------------------------------
__global__ __launch_bounds__(512) void prep_all(
    const int* __restrict__ erow, const int* __restrict__ ecol,
    const float* __restrict__ emb, const float* __restrict__ W1,
    const float* __restrict__ W2,
    int* __restrict__ rsptr, int* __restrict__ colmap, int* __restrict__ epk,
    short* __restrict__ E1, short* __restrict__ W2T)
{
    const int t = threadIdx.x;
    if (blockIdx.x != 0) {
        int g = (blockIdx.x - 1) * 512 + t;     // 72 x 512 = 36864
        if (g < NUM * HD) {
            int node = g >> 6, dim = g & 63;
            float acc = 0.0f;
            #pragma unroll
            for (int k = 0; k < HD; ++k) acc += emb[node * HD + k] * W1[k * HD + dim];
            E1[g] = (short)f2h(acc);
        } else if (g < NUM * HD + HD * HD) {
            int j = g - NUM * HD;
            int dout = j >> 6, din = j & 63;
            W2T[j] = (short)f2h(W2[din * HD + dout]);
        }
        return;
    }

    __shared__ int   sdeg[NUM];
    __shared__ int   aux[NUM];
    __shared__ float sdv[NUM];
    __shared__ int   rnk[NUM];
    __shared__ int   rdg[NUM];
    __shared__ int   wsum[8];

    const int lane = t & 63, wv = t >> 6;

    sdeg[t] = 0; aux[t] = 0;
    __syncthreads();
    for (int e = t; e < NE; e += 512) atomicAdd(&sdeg[ecol[e]], 1);
    __syncthreads();
    const int deg  = sdeg[t];
    const int pdeg = (deg + 1) & ~1;            // pad to even
    const int dbin = deg < NUM ? deg : NUM - 1;
    sdv[t] = deg > 0 ? rsqrtf((float)deg) : 0.0f;
    atomicAdd(&aux[dbin], 1);
    __syncthreads();
    {
        int v = aux[t];
        #pragma unroll
        for (int ofs = 1; ofs < 64; ofs <<= 1) {
            int sh = __shfl_up(v, ofs, 64);
            if (lane >= ofs) v += sh;
        }
        if (lane == 63) wsum[wv] = v;
        __syncthreads();
        if (t == 0) {
            int s = 0;
            #pragma unroll
            for (int w = 0; w < 8; ++w) { int tmp = wsum[w]; wsum[w] = s; s += tmp; }
        }
        __syncthreads();
        int inc = v + wsum[wv];
        aux[t]  = inc;
        __syncthreads();
        sdeg[t] = (t == 0) ? 0 : aux[t - 1];
        __syncthreads();
    }
    {
        int r = atomicAdd(&sdeg[dbin], 1);      // degree-sorted rank
        rnk[t] = r;
        rdg[r] = pdeg;
        colmap[r] = t;
    }
    __syncthreads();
    {
        int dv = rdg[t], v = dv;
        #pragma unroll
        for (int ofs = 1; ofs < 64; ofs <<= 1) {
            int sh = __shfl_up(v, ofs, 64);
            if (lane >= ofs) v += sh;
        }
        if (lane == 63) wsum[wv] = v;
        __syncthreads();
        if (t == 0) {
            int s = 0;
            #pragma unroll
            for (int w = 0; w < 8; ++w) { int tmp = wsum[w]; wsum[w] = s; s += tmp; }
        }
        __syncthreads();
        int inc  = v + wsum[wv];
        int excl = inc - dv;
        rsptr[t] = excl;
        if (t == NUM - 1) rsptr[NUM] = inc;
        aux[t] = excl;
        __syncthreads();
    }
    sdeg[t] = aux[rnk[t]];
    __syncthreads();
    for (int i = t; i < NEP; i += 512) epk[i] = 0;
    __syncthreads();
    for (int e = t; e < NE; e += 512) {
        int c = ecol[e], rr = erow[e];
        int p = atomicAdd(&sdeg[c], 1);
        unsigned ns = (unsigned)f2h(sdv[rr] * sdv[c]);
        epk[p] = (rr << 23) | (int)ns;          // hi16 = row*128
    }
}

// ---------------------------------------------------------------------------
// Body: one block (1024 thr, 16 waves) per BATCH PAIR (b0=2*blk, b0+1).
// R14 structure with MACROW forced to v_fma_mix_f32 (inline asm): each MAC
// consumes the packed f16 halves directly from the raw u32 registers, and
// the edge norm comes straight from the low half of the packed edge word —
// no cvt, no extract, exactly 8 VALU inst per edge per lane.
// ---------------------------------------------------------------------------
__global__ __launch_bounds__(1024, 4) void gcn_body(
    const float* __restrict__ x, const hlf* __restrict__ E1,
    const hlf* __restrict__ W2T,
    const float* __restrict__ b1, const float* __restrict__ b2,
    const float* __restrict__ W3, const float* __restrict__ b3,
    const int* __restrict__ rsptrg, const int* __restrict__ colmapg,
    const int* __restrict__ epkg,
    float* __restrict__ out)
{
    __shared__ hlf   H[NUM * 128];     // 131072 B: B1pair/h1pair/gpair; slog overlay
    __shared__ int   eps[NEP];         // 18432 B
    __shared__ int   sptr[513];
    __shared__ int   cmap[NUM];
    __shared__ float xs[2 * NUM];      // x-pair, then tv-pair
    __shared__ float sred[4];

    float* slog = (float*)H;           // 2x512 logits after SpMM2

    const int t    = threadIdx.x;
    const int b0   = blockIdx.x * 2;
    const int lane = t & 63;
    const int wave = t >> 6;           // 0..15
    const int q    = lane >> 4;        // 0..3
    const int l15  = lane & 15;
    const int gid  = t >> 4;           // 0..63: 16-lane group
    const int j16  = t & 15;           // lane within group
    const int bsel = j16 >> 3;         // batch half served by this lane
    const int d8   = (j16 & 7) * 8;    // dim strip within the half

    // ---- stage edges + csr + x-pair
    {
        const int4* g4 = (const int4*)epkg;
        *(int4*)&eps[t * 4] = g4[t];                       // 4096 ints
        if (t < 128) *(int4*)&eps[4096 + t * 4] = g4[1024 + t];
    }
    if (t < 513) sptr[t] = rsptrg[t];
    if (t < NUM) cmap[t] = colmapg[t];
    xs[t] = x[b0 * NUM + t];           // rows b0 and b0+1, contiguous
    __syncthreads();

    // ---- build H = B1-pair: H[node][bs*64+d] = x[bs][node] * E1[node][d]
    #pragma unroll
    for (int p = 0; p < 8; ++p) {
        int i = t + p * 1024;          // 8192 chunks of 8 halfs
        int node = i >> 4, sub = i & 15;
        int bs = sub >> 3, dd = (sub & 7) * 8;
        hlf  xh = (hlf)xs[bs * NUM + node];
        hlf8 e  = *(const hlf8*)&E1[node * HD + dd];
        hlf8 o;
        #pragma unroll
        for (int j = 0; j < 8; ++j) o[j] = e[j] * xh;
        *(hlf8*)((char*)H + node * 256 + bs * 128 + dd * 2) = o;
    }
    const char* Hb = (const char*)H + j16 * 16;   // per-lane gather base
    __syncthreads();

// v_fma_mix_f32: ACC += (f16 half of SRC) * (f16 low half of NRM)
// op_sel_hi:[1,1,0] marks src0/src1 as f16; op_sel[0] picks lo/hi of SRC.
#define FMIXL(ACC, SRC, NRM)                                                  \
    asm("v_fma_mix_f32 %0, %1, %2, %0 op_sel:[0,0,0] op_sel_hi:[1,1,0]"       \
        : "+v"(ACC) : "v"(SRC), "v"(NRM));
#define FMIXH(ACC, SRC, NRM)                                                  \
    asm("v_fma_mix_f32 %0, %1, %2, %0 op_sel:[1,0,0] op_sel_hi:[1,1,0]"       \
        : "+v"(ACC) : "v"(SRC), "v"(NRM));

// 8 mix-FMAs into acc; norm is consumed in-place from the packed edge word
#define MACROW(acc, hv, pe) {                                                 \
        FMIXL(acc[0], (hv).x, (pe)) FMIXH(acc[1], (hv).x, (pe))               \
        FMIXL(acc[2], (hv).y, (pe)) FMIXH(acc[3], (hv).y, (pe))               \
        FMIXL(acc[4], (hv).z, (pe)) FMIXH(acc[5], (hv).z, (pe))               \
        FMIXL(acc[6], (hv).w, (pe)) FMIXH(acc[7], (hv).w, (pe)) }

// pair-row byte offset: hi16(pe) = row*128 -> *2 = row*256
#define LDROWP(d, pe) d = *(const uint4*)(Hb + (((unsigned)(pe) >> 16) << 1));

// one SpMM1 rank: accumulate, bias+relu, pack into the named hold HV
#define SPMM1_SET(SET, HV) {                                                  \
        int r  = (SET) * 64 + gid;                                            \
        int e0 = sptr[r], e1 = sptr[r + 1];                                   \
        float a[8];                                                           \
        _Pragma("unroll")                                                     \
        for (int j = 0; j < 8; ++j) a[j] = 0.0f;                              \
        for (int e = e0; e < e1; e += 2) {                                    \
            int2 qa = *(const int2*)&eps[e];                                  \
            uint4 c0, c1;                                                     \
            LDROWP(c0, qa.x) LDROWP(c1, qa.y)                                 \
            MACROW(a, c0, qa.x) MACROW(a, c1, qa.y)                           \
        }                                                                     \
        f32x4 u0 = *(const f32x4*)&b1[d8];                                    \
        f32x4 u1 = *(const f32x4*)&b1[d8 + 4];                                \
        HV.x = __builtin_bit_cast(unsigned, __builtin_amdgcn_cvt_pkrtz(       \
                   fmaxf(a[0] + u0[0], 0.0f), fmaxf(a[1] + u0[1], 0.0f)));    \
        HV.y = __builtin_bit_cast(unsigned, __builtin_amdgcn_cvt_pkrtz(       \
                   fmaxf(a[2] + u0[2], 0.0f), fmaxf(a[3] + u0[3], 0.0f)));    \
        HV.z = __builtin_bit_cast(unsigned, __builtin_amdgcn_cvt_pkrtz(       \
                   fmaxf(a[4] + u1[0], 0.0f), fmaxf(a[5] + u1[1], 0.0f)));    \
        HV.w = __builtin_bit_cast(unsigned, __builtin_amdgcn_cvt_pkrtz(       \
                   fmaxf(a[6] + u1[2], 0.0f), fmaxf(a[7] + u1[3], 0.0f)));    }

#define SPMM1_WB(SET, HV) {                                                   \
        int r = (SET) * 64 + gid;                                             \
        *(uint4*)((char*)H + cmap[r] * 256 + bsel * 128 + d8 * 2) = HV;       }

    // ---- SpMM1: h1 = relu(S@B1 + b1); named register holds, in-place write
    {
        uint4 hv0, hv1, hv2, hv3, hv4, hv5, hv6, hv7;
        SPMM1_SET(0, hv0) SPMM1_SET(1, hv1) SPMM1_SET(2, hv2) SPMM1_SET(3, hv3)
        SPMM1_SET(4, hv4) SPMM1_SET(5, hv5) SPMM1_SET(6, hv6) SPMM1_SET(7, hv7)
        __syncthreads();   // all B1 gathers complete
        SPMM1_WB(0, hv0) SPMM1_WB(1, hv1) SPMM1_WB(2, hv2) SPMM1_WB(3, hv3)
        SPMM1_WB(4, hv4) SPMM1_WB(5, hv5) SPMM1_WB(6, hv6) SPMM1_WB(7, hv7)
    }
    __syncthreads();

    // ---- MFMA: g = h1 @ W2 (H viewed as 1024x64 f16, row = node*2+bsel)
    {
        uint2 gk[4][4];
        #pragma unroll
        for (int mm = 0; mm < 4; ++mm) {
            int m = wave * 64 + mm * 16 + l15;
            hlf8 a0 = *(const hlf8*)((const char*)H + m * 128 + q * 16);
            hlf8 a1 = *(const hlf8*)((const char*)H + m * 128 + 64 + q * 16);
            #pragma unroll
            for (int nt = 0; nt < 4; ++nt) {
                hlf8 w0 = *(const hlf8*)&W2T[(nt * 16 + l15) * HD + q * 8];
                hlf8 w1 = *(const hlf8*)&W2T[(nt * 16 + l15) * HD + 32 + q * 8];
                f32x4 acc = (f32x4){0.f, 0.f, 0.f, 0.f};
                acc = __builtin_amdgcn_mfma_f32_16x16x32_f16(a0, w0, acc, 0, 0, 0);
                acc = __builtin_amdgcn_mfma_f32_16x16x32_f16(a1, w1, acc, 0, 0, 0);
                gk[mm][nt].x = __builtin_bit_cast(unsigned,
                                   __builtin_amdgcn_cvt_pkrtz(acc[0], acc[1]));
                gk[mm][nt].y = __builtin_bit_cast(unsigned,
                                   __builtin_amdgcn_cvt_pkrtz(acc[2], acc[3]));
            }
        }
        __syncthreads();   // all h1 reads complete
        #pragma unroll
        for (int mm = 0; mm < 4; ++mm)
            #pragma unroll
            for (int nt = 0; nt < 4; ++nt) {
                int mrow = wave * 64 + mm * 16 + q * 4;
                hlf2 lo = __builtin_bit_cast(hlf2, gk[mm][nt].x);
                hlf2 hi = __builtin_bit_cast(hlf2, gk[mm][nt].y);
                H[(mrow + 0) * HD + nt * 16 + l15] = lo[0];
                H[(mrow + 1) * HD + nt * 16 + l15] = lo[1];
                H[(mrow + 2) * HD + nt * 16 + l15] = hi[0];
                H[(mrow + 3) * HD + nt * 16 + l15] = hi[1];
            }
    }
    __syncthreads();

    // ---- SpMM2 + epilogue: tv[bsel][c] = sum_d relu((S@g)[c,d]+b2[d])*W3[d]
    #pragma unroll 1
    for (int set = 0; set < 8; ++set) {
        int r  = set * 64 + gid;
        int e0 = sptr[r], e1 = sptr[r + 1];
        int c  = cmap[r];
        float a[8];
        #pragma unroll
        for (int j = 0; j < 8; ++j) a[j] = 0.0f;
        int e = e0;
        for (; e + 4 <= e1; e += 4) {
            int2 qa = *(const int2*)&eps[e];
            int2 qb = *(const int2*)&eps[e + 2];
            uint4 c0, c1, c2, c3;
            LDROWP(c0, qa.x) LDROWP(c1, qa.y) LDROWP(c2, qb.x) LDROWP(c3, qb.y)
            MACROW(a, c0, qa.x) MACROW(a, c1, qa.y)
            MACROW(a, c2, qb.x) MACROW(a, c3, qb.y)
        }
        if (e < e1) {
            int2 qa = *(const int2*)&eps[e];
            uint4 c0, c1;
            LDROWP(c0, qa.x) LDROWP(c1, qa.y)
            MACROW(a, c0, qa.x) MACROW(a, c1, qa.y)
        }
        f32x4 v0 = *(const f32x4*)&b2[d8], v1 = *(const f32x4*)&b2[d8 + 4];
        f32x4 w0 = *(const f32x4*)&W3[d8], w1 = *(const f32x4*)&W3[d8 + 4];
        float v = 0.0f;
        #pragma unroll
        for (int j = 0; j < 4; ++j) {
            v += fmaxf(a[j] + v0[j], 0.0f) * w0[j];
            v += fmaxf(a[j + 4] + v1[j], 0.0f) * w1[j];
        }
        v += __shfl_xor(v, 1, 64);
        v += __shfl_xor(v, 2, 64);
        v += __shfl_xor(v, 4, 64);
        if ((t & 7) == 0) xs[bsel * NUM + c] = v;   // xs now tv-pair
    }
    __syncthreads();

    // ---- SpMM3: logits = S@tv + b3  (one (rank, batch-half) per thread)
    {
        int bs = t >> 9, rk = t & 511;
        int e0 = sptr[rk], e1 = sptr[rk + 1];
        const float* TVB = xs + bs * NUM;
        float acc = 0.0f;
        for (int e = e0; e < e1; ++e) {
            unsigned pe = (unsigned)eps[e];
            float nf = (float)__builtin_bit_cast(hlf2, pe)[0];
            acc = fmaf(nf, TVB[pe >> 23], acc);
        }
        slog[bs * NUM + cmap[rk]] = acc + b3[0];
    }
    __syncthreads();

    // ---- softmax stats over [0, MAIN) for each element
    if (t < 128) {
        int bs = t >> 6, l = t & 63;
        float v = (l < MAIN) ? slog[bs * NUM + l] : -1e30f;
        float m = v;
        m = fmaxf(m, __shfl_xor(m, 1, 64));
        m = fmaxf(m, __shfl_xor(m, 2, 64));
        m = fmaxf(m, __shfl_xor(m, 4, 64));
        m = fmaxf(m, __shfl_xor(m, 8, 64));
        float ev = (l < MAIN) ? __expf(v - m) : 0.0f;
        ev += __shfl_xor(ev, 1, 64);
        ev += __shfl_xor(ev, 2, 64);
        ev += __shfl_xor(ev, 4, 64);
        ev += __shfl_xor(ev, 8, 64);
        if (l == 0) { sred[bs * 2] = m; sred[bs * 2 + 1] = ev; }
    }
    __syncthreads();

    {
        int bs = t >> 9, rk = t & 511;
        float l = slog[bs * NUM + rk];
        float o = (rk < MAIN) ? __expf(l - sred[bs * 2]) / sred[bs * 2 + 1]
                              : 1.0f / (1.0f + __expf(-l));
        out[(b0 + bs) * NUM + rk] = o;
    }
#undef MACROW
#undef LDROWP
#undef FMIXL
#undef FMIXH
#undef SPMM1_SET
#undef SPMM1_WB
}

// ---------------------------------------------------------------------------
extern "C" void kernel_launch(void* const* d_in, const int* in_sizes, int n_in,
                              void* d_out, int out_size, void* d_ws, size_t ws_size,
                              hipStream_t stream) {
    const float* x    = (const float*)d_in[0];
    const float* emb  = (const float*)d_in[1];
    const float* W1   = (const float*)d_in[2];
    const float* b1   = (const float*)d_in[3];
    const float* W2   = (const float*)d_in[4];
    const float* b2   = (const float*)d_in[5];
    const float* W3   = (const float*)d_in[6];
    const float* b3   = (const float*)d_in[7];
    const int*   erow = (const int*)d_in[8];
    const int*   ecol = (const int*)d_in[9];

    char* ws = (char*)d_ws;
    int*   rsptr  = (int*)ws;                // 513 ints  [0, 2052)
    int*   colmap = (int*)(ws + 2176);       // 512 ints  [2176, 4224)
    int*   epk    = (int*)(ws + 4224);       // 4608 ints [4224, 22656)
    short* E1     = (short*)(ws + 22656);    // 32768 f16 [22656, 88192)
    short* W2T    = (short*)(ws + 88192);    // 4096 f16  [88192, 96384)

    prep_all<<<73, 512, 0, stream>>>(erow, ecol, emb, W1, W2,
                                     rsptr, colmap, epk, E1, W2T);
    gcn_body<<<NB / 2, 1024, 0, stream>>>(x, (const hlf*)E1, (const hlf*)W2T,
                                          b1, b2, W3, b3,
                                          rsptr, colmap, epk, (float*)d_out);
}

// Round 16
// 136.220 us; speedup vs baseline: 1.4384x; 1.0375x over previous
//
#include <hip/hip_runtime.h>
#include <stdint.h>

#define NB    1024   // batch
#define NUM   512    // nodes
#define HD    64     // hidden dim
#define NE    4096   // edges
#define NEP   4608   // padded edge capacity (each column padded to even count)
#define MAIN  10     // softmax segment

typedef _Float16 hlf;
typedef __attribute__((ext_vector_type(2))) _Float16 hlf2;
typedef __attribute__((ext_vector_type(8))) _Float16 hlf8;
typedef __attribute__((ext_vector_type(4))) float f32x4;

__device__ __forceinline__ unsigned short f2h(float f) {
    hlf v = (hlf)f;
    return __builtin_bit_cast(unsigned short, v);
}

// ---------------------------------------------------------------------------
// Prep (identical to the proven R6/R14 kernel): block 0 builds degree-sorted,
// even-padded CSR via wave-shfl scans; blocks 1..72 cast E1 = emb@W1 and
// W2T = W2^T to f16. Edge pack: epk = (row << 23) | f16(norm).
// ---------------------------------------------------------------------------
__global__ __launch_bounds__(512) void prep_all(
    const int* __restrict__ erow, const int* __restrict__ ecol,
    const float* __restrict__ emb, const float* __restrict__ W1,
    const float* __restrict__ W2,
    int* __restrict__ rsptr, int* __restrict__ colmap, int* __restrict__ epk,
    short* __restrict__ E1, short* __restrict__ W2T)
{
    const int t = threadIdx.x;
    if (blockIdx.x != 0) {
        int g = (blockIdx.x - 1) * 512 + t;     // 72 x 512 = 36864
        if (g < NUM * HD) {
            int node = g >> 6, dim = g & 63;
            float acc = 0.0f;
            #pragma unroll
            for (int k = 0; k < HD; ++k) acc += emb[node * HD + k] * W1[k * HD + dim];
            E1[g] = (short)f2h(acc);
        } else if (g < NUM * HD + HD * HD) {
            int j = g - NUM * HD;
            int dout = j >> 6, din = j & 63;
            W2T[j] = (short)f2h(W2[din * HD + dout]);
        }
        return;
    }

    __shared__ int   sdeg[NUM];
    __shared__ int   aux[NUM];
    __shared__ float sdv[NUM];
    __shared__ int   rnk[NUM];
    __shared__ int   rdg[NUM];
    __shared__ int   wsum[8];

    const int lane = t & 63, wv = t >> 6;

    sdeg[t] = 0; aux[t] = 0;
    __syncthreads();
    for (int e = t; e < NE; e += 512) atomicAdd(&sdeg[ecol[e]], 1);
    __syncthreads();
    const int deg  = sdeg[t];
    const int pdeg = (deg + 1) & ~1;            // pad to even
    const int dbin = deg < NUM ? deg : NUM - 1;
    sdv[t] = deg > 0 ? rsqrtf((float)deg) : 0.0f;
    atomicAdd(&aux[dbin], 1);
    __syncthreads();
    {
        int v = aux[t];
        #pragma unroll
        for (int ofs = 1; ofs < 64; ofs <<= 1) {
            int sh = __shfl_up(v, ofs, 64);
            if (lane >= ofs) v += sh;
        }
        if (lane == 63) wsum[wv] = v;
        __syncthreads();
        if (t == 0) {
            int s = 0;
            #pragma unroll
            for (int w = 0; w < 8; ++w) { int tmp = wsum[w]; wsum[w] = s; s += tmp; }
        }
        __syncthreads();
        int inc = v + wsum[wv];
        aux[t]  = inc;
        __syncthreads();
        sdeg[t] = (t == 0) ? 0 : aux[t - 1];
        __syncthreads();
    }
    {
        int r = atomicAdd(&sdeg[dbin], 1);      // degree-sorted rank
        rnk[t] = r;
        rdg[r] = pdeg;
        colmap[r] = t;
    }
    __syncthreads();
    {
        int dv = rdg[t], v = dv;
        #pragma unroll
        for (int ofs = 1; ofs < 64; ofs <<= 1) {
            int sh = __shfl_up(v, ofs, 64);
            if (lane >= ofs) v += sh;
        }
        if (lane == 63) wsum[wv] = v;
        __syncthreads();
        if (t == 0) {
            int s = 0;
            #pragma unroll
            for (int w = 0; w < 8; ++w) { int tmp = wsum[w]; wsum[w] = s; s += tmp; }
        }
        __syncthreads();
        int inc  = v + wsum[wv];
        int excl = inc - dv;
        rsptr[t] = excl;
        if (t == NUM - 1) rsptr[NUM] = inc;
        aux[t] = excl;
        __syncthreads();
    }
    sdeg[t] = aux[rnk[t]];
    __syncthreads();
    for (int i = t; i < NEP; i += 512) epk[i] = 0;
    __syncthreads();
    for (int e = t; e < NE; e += 512) {
        int c = ecol[e], rr = erow[e];
        int p = atomicAdd(&sdeg[c], 1);
        unsigned ns = (unsigned)f2h(sdv[rr] * sdv[c]);
        epk[p] = (rr << 23) | (int)ns;          // hi16 = row*128 (byte offset)
    }
}

// ---------------------------------------------------------------------------
// Body: one block (1024 thr, 16 waves) per batch element; 2 blocks/CU
// (73.7 KB LDS, launch_bounds(1024,8), total regs engineered <= 64):
//  - eps read from GLOBAL (18 KB, L1-hot, shared by co-resident blocks)
//  - SpMM1: 4 sets x 128 8-lane groups; only 4 named uint4 holds (16 regs)
//  - MFMA : g = h1@W2 is ROW-WISE -> each wave reads/writes only its own
//    32 rows: read-fragments -> MFMA -> write in place, NO holds, NO extra
//    barrier (cross-wave hazard impossible)
//  - SpMM2: 4-edge chunks, no holds
//  - all MACs are v_fma_mix_f32 (R15)
// ---------------------------------------------------------------------------
__global__ __launch_bounds__(1024, 8) void gcn_body(
    const float* __restrict__ x, const hlf* __restrict__ E1,
    const hlf* __restrict__ W2T,
    const float* __restrict__ b1, const float* __restrict__ b2,
    const float* __restrict__ W3, const float* __restrict__ b3,
    const int* __restrict__ rsptrg, const int* __restrict__ colmapg,
    const int* __restrict__ epkg,
    float* __restrict__ out)
{
    __shared__ hlf   H[NUM * HD];      // 65536 B, time-shared: B1 / h1 / g
    __shared__ int   sptr[513];
    __shared__ int   cmap[NUM];
    __shared__ float tv[NUM];
    __shared__ float slog[NUM];
    __shared__ float sred[2];

    const int t     = threadIdx.x;
    const int b     = blockIdx.x;
    const int lane  = t & 63;
    const int wave  = t >> 6;          // 0..15
    const int q     = lane >> 4;
    const int l15   = lane & 15;
    const int gid   = t >> 3;          // 0..127: 8-lane group
    const int dbase = (lane & 7) * 8;  // this lane's 8-dim strip

    if (t < 513) sptr[t] = rsptrg[t];
    if (t < NUM) cmap[t] = colmapg[t];

    // ---- build H = B1: B1[r][d] = x[b,r] * E1[r][d]   (f16 storage)
    #pragma unroll
    for (int p = 0; p < 4; ++p) {
        int i = t + p * 1024;
        int r = i >> 3, d8 = (i & 7) * 8;
        float xr = x[b * NUM + r];
        hlf  xh = (hlf)xr;
        hlf8 e  = *(const hlf8*)&E1[r * HD + d8];
        hlf8 o;
        #pragma unroll
        for (int j = 0; j < 8; ++j) o[j] = e[j] * xh;
        *(hlf8*)&H[r * HD + d8] = o;
    }
    const char* Hb = (const char*)H + dbase * 2;   // per-lane gather base
    __syncthreads();

// v_fma_mix_f32: ACC += (f16 half of SRC) * (f16 low half of NRM)
#define FMIXL(ACC, SRC, NRM)                                                  \
    asm("v_fma_mix_f32 %0, %1, %2, %0 op_sel:[0,0,0] op_sel_hi:[1,1,0]"       \
        : "+v"(ACC) : "v"(SRC), "v"(NRM));
#define FMIXH(ACC, SRC, NRM)                                                  \
    asm("v_fma_mix_f32 %0, %1, %2, %0 op_sel:[1,0,0] op_sel_hi:[1,1,0]"       \
        : "+v"(ACC) : "v"(SRC), "v"(NRM));

#define MACROW(acc, hv, pe) {                                                 \
        FMIXL(acc[0], (hv).x, (pe)) FMIXH(acc[1], (hv).x, (pe))               \
        FMIXL(acc[2], (hv).y, (pe)) FMIXH(acc[3], (hv).y, (pe))               \
        FMIXL(acc[4], (hv).z, (pe)) FMIXH(acc[5], (hv).z, (pe))               \
        FMIXL(acc[6], (hv).w, (pe)) FMIXH(acc[7], (hv).w, (pe)) }

// hi16(pe) = row*128 = byte offset into 128B rows
#define LDROW(d, pe) d = *(const uint4*)(Hb + ((unsigned)(pe) >> 16));

// one SpMM1 rank: accumulate, bias+relu, pack into the named hold HV
#define SPMM1_SET(SET, HV) {                                                  \
        int r  = (SET) * 128 + gid;                                           \
        int e0 = sptr[r], e1 = sptr[r + 1];                                   \
        float a[8];                                                           \
        _Pragma("unroll")                                                     \
        for (int j = 0; j < 8; ++j) a[j] = 0.0f;                              \
        for (int e = e0; e < e1; e += 2) {                                    \
            int2 qa = *(const int2*)&epkg[e];                                 \
            uint4 c0, c1;                                                     \
            LDROW(c0, qa.x) LDROW(c1, qa.y)                                   \
            MACROW(a, c0, qa.x) MACROW(a, c1, qa.y)                           \
        }                                                                     \
        f32x4 u0 = *(const f32x4*)&b1[dbase];                                 \
        f32x4 u1 = *(const f32x4*)&b1[dbase + 4];                             \
        HV.x = __builtin_bit_cast(unsigned, __builtin_amdgcn_cvt_pkrtz(       \
                   fmaxf(a[0] + u0[0], 0.0f), fmaxf(a[1] + u0[1], 0.0f)));    \
        HV.y = __builtin_bit_cast(unsigned, __builtin_amdgcn_cvt_pkrtz(       \
                   fmaxf(a[2] + u0[2], 0.0f), fmaxf(a[3] + u0[3], 0.0f)));    \
        HV.z = __builtin_bit_cast(unsigned, __builtin_amdgcn_cvt_pkrtz(       \
                   fmaxf(a[4] + u1[0], 0.0f), fmaxf(a[5] + u1[1], 0.0f)));    \
        HV.w = __builtin_bit_cast(unsigned, __builtin_amdgcn_cvt_pkrtz(       \
                   fmaxf(a[6] + u1[2], 0.0f), fmaxf(a[7] + u1[3], 0.0f)));    }

#define SPMM1_WB(SET, HV) {                                                   \
        int r = (SET) * 128 + gid;                                            \
        *(uint4*)&H[cmap[r] * HD + dbase] = HV;                               }

    // ---- SpMM1: h1 = relu(S@B1 + b1); 4 named holds, in-place write
    {
        uint4 hv0, hv1, hv2, hv3;
        SPMM1_SET(0, hv0) SPMM1_SET(1, hv1) SPMM1_SET(2, hv2) SPMM1_SET(3, hv3)
        __syncthreads();   // all B1 gathers complete
        SPMM1_WB(0, hv0) SPMM1_WB(1, hv1) SPMM1_WB(2, hv2) SPMM1_WB(3, hv3)
    }
    __syncthreads();       // h1 complete

    // ---- MFMA: g = h1 @ W2, row-wise in place (wave-private rows, no holds)
    {
        #pragma unroll
        for (int mm = 0; mm < 2; ++mm) {
            int m = wave * 32 + mm * 16 + l15;
            hlf8 a0 = *(const hlf8*)&H[m * HD + q * 8];
            hlf8 a1 = *(const hlf8*)&H[m * HD + 32 + q * 8];
            uint2 gk0, gk1, gk2, gk3;
            #pragma unroll
            for (int nt = 0; nt < 4; ++nt) {
                hlf8 w0 = *(const hlf8*)&W2T[(nt * 16 + l15) * HD + q * 8];
                hlf8 w1 = *(const hlf8*)&W2T[(nt * 16 + l15) * HD + 32 + q * 8];
                f32x4 acc = (f32x4){0.f, 0.f, 0.f, 0.f};
                acc = __builtin_amdgcn_mfma_f32_16x16x32_f16(a0, w0, acc, 0, 0, 0);
                acc = __builtin_amdgcn_mfma_f32_16x16x32_f16(a1, w1, acc, 0, 0, 0);
                uint2 pk;
                pk.x = __builtin_bit_cast(unsigned,
                           __builtin_amdgcn_cvt_pkrtz(acc[0], acc[1]));
                pk.y = __builtin_bit_cast(unsigned,
                           __builtin_amdgcn_cvt_pkrtz(acc[2], acc[3]));
                if (nt == 0) gk0 = pk;
                else if (nt == 1) gk1 = pk;
                else if (nt == 2) gk2 = pk;
                else gk3 = pk;
            }
            // write this 16-row tile (reads of it are complete; rows are
            // wave-private so no block barrier needed)
            int mrow = wave * 32 + mm * 16 + q * 4;
            #pragma unroll
            for (int nt = 0; nt < 4; ++nt) {
                uint2 pk = (nt == 0) ? gk0 : (nt == 1) ? gk1
                         : (nt == 2) ? gk2 : gk3;
                hlf2 lo = __builtin_bit_cast(hlf2, pk.x);
                hlf2 hi = __builtin_bit_cast(hlf2, pk.y);
                H[(mrow + 0) * HD + nt * 16 + l15] = lo[0];
                H[(mrow + 1) * HD + nt * 16 + l15] = lo[1];
                H[(mrow + 2) * HD + nt * 16 + l15] = hi[0];
                H[(mrow + 3) * HD + nt * 16 + l15] = hi[1];
            }
        }
    }
    __syncthreads();       // g complete

    // ---- SpMM2 + epilogue: tv[c] = sum_d relu((S@g)[c,d] + b2[d]) * W3[d]
    #pragma unroll 1
    for (int set = 0; set < 4; ++set) {
        int r  = set * 128 + gid;
        int e0 = sptr[r], e1 = sptr[r + 1];
        int c  = cmap[r];
        float a[8];
        #pragma unroll
        for (int j = 0; j < 8; ++j) a[j] = 0.0f;
        int e = e0;
        for (; e + 4 <= e1; e += 4) {
            int2 qa = *(const int2*)&epkg[e];
            int2 qb = *(const int2*)&epkg[e + 2];
            uint4 c0, c1, c2, c3;
            LDROW(c0, qa.x) LDROW(c1, qa.y) LDROW(c2, qb.x) LDROW(c3, qb.y)
            MACROW(a, c0, qa.x) MACROW(a, c1, qa.y)
            MACROW(a, c2, qb.x) MACROW(a, c3, qb.y)
        }
        if (e < e1) {
            int2 qa = *(const int2*)&epkg[e];
            uint4 c0, c1;
            LDROW(c0, qa.x) LDROW(c1, qa.y)
            MACROW(a, c0, qa.x) MACROW(a, c1, qa.y)
        }
        f32x4 v0 = *(const f32x4*)&b2[dbase], v1 = *(const f32x4*)&b2[dbase + 4];
        f32x4 w0 = *(const f32x4*)&W3[dbase], w1 = *(const f32x4*)&W3[dbase + 4];
        float v = 0.0f;
        #pragma unroll
        for (int j = 0; j < 4; ++j) {
            v += fmaxf(a[j] + v0[j], 0.0f) * w0[j];
            v += fmaxf(a[j + 4] + v1[j], 0.0f) * w1[j];
        }
        v += __shfl_xor(v, 1, 64);
        v += __shfl_xor(v, 2, 64);
        v += __shfl_xor(v, 4, 64);
        if ((lane & 7) == 0) tv[c] = v;
    }
    __syncthreads();

    // ---- SpMM3: slog[col] = (S @ tv)[col] + b3   (2 threads per rank)
    {
        int rk = t >> 1, hh = t & 1;
        int e0 = sptr[rk], e1 = sptr[rk + 1];
        int mid = (e0 + e1) >> 1;
        int ea = hh ? mid : e0;
        int eb = hh ? e1 : mid;
        float acc = 0.0f;
        for (int e = ea; e < eb; ++e) {
            unsigned pe = (unsigned)epkg[e];
            float nf = (float)__builtin_bit_cast(hlf2, pe)[0];
            acc = fmaf(nf, *(const float*)((const char*)tv + (pe >> 21)), acc);
        }
        acc += __shfl_xor(acc, 1, 64);
        if (!hh) slog[cmap[rk]] = acc + b3[0];
    }
    __syncthreads();

    // ---- softmax stats over [0, MAIN)
    if (t < 64) {
        float v = (t < MAIN) ? slog[t] : -1e30f;
        float m = v;
        m = fmaxf(m, __shfl_xor(m, 1, 64));
        m = fmaxf(m, __shfl_xor(m, 2, 64));
        m = fmaxf(m, __shfl_xor(m, 4, 64));
        m = fmaxf(m, __shfl_xor(m, 8, 64));
        float ev = (t < MAIN) ? __expf(v - m) : 0.0f;
        ev += __shfl_xor(ev, 1, 64);
        ev += __shfl_xor(ev, 2, 64);
        ev += __shfl_xor(ev, 4, 64);
        ev += __shfl_xor(ev, 8, 64);
        if (t == 0) { sred[0] = m; sred[1] = ev; }
    }
    __syncthreads();

    if (t < NUM) {
        float l = slog[t];
        float o = (t < MAIN) ? __expf(l - sred[0]) / sred[1]
                             : 1.0f / (1.0f + __expf(-l));
        out[b * NUM + t] = o;
    }
#undef MACROW
#undef LDROW
#undef FMIXL
#undef FMIXH
#undef SPMM1_SET
#undef SPMM1_WB
}

// ---------------------------------------------------------------------------
extern "C" void kernel_launch(void* const* d_in, const int* in_sizes, int n_in,
                              void* d_out, int out_size, void* d_ws, size_t ws_size,
                              hipStream_t stream) {
    const float* x    = (const float*)d_in[0];
    const float* emb  = (const float*)d_in[1];
    const float* W1   = (const float*)d_in[2];
    const float* b1   = (const float*)d_in[3];
    const float* W2   = (const float*)d_in[4];
    const float* b2   = (const float*)d_in[5];
    const float* W3   = (const float*)d_in[6];
    const float* b3   = (const float*)d_in[7];
    const int*   erow = (const int*)d_in[8];
    const int*   ecol = (const int*)d_in[9];

    char* ws = (char*)d_ws;
    int*   rsptr  = (int*)ws;                // 513 ints  [0, 2052)
    int*   colmap = (int*)(ws + 2176);       // 512 ints  [2176, 4224)
    int*   epk    = (int*)(ws + 4224);       // 4608 ints [4224, 22656)
    short* E1     = (short*)(ws + 22656);    // 32768 f16 [22656, 88192)
    short* W2T    = (short*)(ws + 88192);    // 4096 f16  [88192, 96384)

    prep_all<<<73, 512, 0, stream>>>(erow, ecol, emb, W1, W2,
                                     rsptr, colmap, epk, E1, W2T);
    gcn_body<<<NB, 1024, 0, stream>>>(x, (const hlf*)E1, (const hlf*)W2T,
                                      b1, b2, W3, b3,
                                      rsptr, colmap, epk, (float*)d_out);
}